// Round 4
// baseline (845.193 us; speedup 1.0000x reference)
//
#include <hip/hip_runtime.h>
#include <math.h>

// ---------------------------------------------------------------------------
// BimodalCompressor: KPConv point network (round 4)
// fp32 compute, bf16 internal activations, FLOAT32 outputs (d_out is float*:
// round-3 failure decoded as ushort writes landing at half-scale offsets).
// N=40000 pts, K=32 neighbors, P=15 kernel pts, C=128 channels.
// BN: training mode, biased var, eps=1e-5. LeakyReLU slope 0.01.
// ---------------------------------------------------------------------------

#define NPTS 40000
#define KNB  32
#define PKP  15
#define SLOPE 0.01f
#define BNEPS 1e-5f
#define INV_N (1.0f/40000.0f)

__device__ __forceinline__ float lrelu(float x){ return x >= 0.0f ? x : SLOPE*x; }
__device__ __forceinline__ unsigned short f2bf(float f){
  unsigned int b = __float_as_uint(f);
  b += 0x7fffu + ((b>>16)&1u);            // round-to-nearest-even
  return (unsigned short)(b>>16);
}
__device__ __forceinline__ float bf2f(unsigned short u){
  return __uint_as_float(((unsigned int)u)<<16);
}

// --------------------------------------------------------------------------
// K1: preact(bf16) = cov[N,9] @ pre_w[9,128] + pre_b ; stats (fp32 atomics)
// --------------------------------------------------------------------------
__global__ __launch_bounds__(256) void k_pre(
    const float* __restrict__ cov, const float* __restrict__ w,
    const float* __restrict__ b, unsigned short* __restrict__ preact,
    float* __restrict__ stats){
  __shared__ float sW[9*128];
  __shared__ float sX[32*9];
  __shared__ float sSum[2][128], sSq[2][128];
  int tid = threadIdx.x;
  int row0 = blockIdx.x*32;
  for (int i = tid; i < 9*128; i += 256) sW[i] = w[i];
  for (int i = tid; i < 32*9;  i += 256) sX[i] = cov[row0*9 + i];
  __syncthreads();
  int c = tid & 127, h = tid >> 7;
  float bias = b[c];
  float ls = 0.0f, lq = 0.0f;
  for (int r = h*16; r < h*16+16; ++r){
    float acc = bias;
    #pragma unroll
    for (int i = 0; i < 9; ++i) acc += sX[r*9+i]*sW[i*128+c];
    preact[(size_t)(row0+r)*128 + c] = f2bf(acc);
    ls += acc; lq += acc*acc;
  }
  sSum[h][c] = ls; sSq[h][c] = lq;
  __syncthreads();
  if (h == 0){
    atomicAdd(&stats[c],     sSum[0][c]+sSum[1][c]);
    atomicAdd(&stats[128+c], sSq[0][c]+sSq[1][c]);
  }
}

// --------------------------------------------------------------------------
// K2: feat(bf16) = lrelu(bn(preact)) ; fsum[n] (fp32)
// --------------------------------------------------------------------------
__global__ __launch_bounds__(256) void k_prenorm(
    const unsigned short* __restrict__ preact, const float* __restrict__ stats,
    const float* __restrict__ g, const float* __restrict__ b,
    unsigned short* __restrict__ feat, float* __restrict__ fsum){
  int wid  = (int)((blockIdx.x*256 + threadIdx.x) >> 6);
  int lane = threadIdx.x & 63;
  if (wid >= NPTS) return;
  float su = stats[lane], sq = stats[128+lane];
  float mean = su*INV_N, var = sq*INV_N - mean*mean;
  float s0 = g[lane]*rsqrtf(var+BNEPS), h0 = b[lane]-mean*s0;
  su = stats[64+lane]; sq = stats[192+lane];
  mean = su*INV_N; var = sq*INV_N - mean*mean;
  float s1 = g[64+lane]*rsqrtf(var+BNEPS), h1 = b[64+lane]-mean*s1;
  size_t off = (size_t)wid*128;
  float f0 = lrelu(bf2f(preact[off+lane])*s0+h0);
  float f1 = lrelu(bf2f(preact[off+64+lane])*s1+h1);
  feat[off+lane]    = f2bf(f0);
  feat[off+64+lane] = f2bf(f1);
  float t = f0 + f1;
  #pragma unroll
  for (int o = 32; o; o >>= 1) t += __shfl_down(t, o, 64);
  if (lane == 0) fsum[wid] = t;
}

// --------------------------------------------------------------------------
// K3: per point n in [base, base+rows): influences [K,P], gather bf16 feats,
// wtd_chunk[(n-base),p,c] = bf16( sum_k infl[k,p]*feat[idx[k],c] ) ; invn[n]
// --------------------------------------------------------------------------
__global__ __launch_bounds__(128) void k_kpconv(
    const float* __restrict__ pts, const int* __restrict__ nbr,
    const float* __restrict__ kp, const unsigned short* __restrict__ feat,
    const float* __restrict__ fsum, unsigned short* __restrict__ wtd,
    float* __restrict__ invn, float inv_ext, int base){
  int n   = base + blockIdx.x;
  int tid = threadIdx.x;
  __shared__ int   sIdx[KNB];
  __shared__ float sNb[KNB][3];
  __shared__ float sFs[KNB];
  __shared__ float sKP[16][3];
  __shared__ float sInfl[KNB][16];   // padded P 15->16 for float4 reads
  if (tid < PKP){
    sKP[tid][0]=kp[tid*3+0]; sKP[tid][1]=kp[tid*3+1]; sKP[tid][2]=kp[tid*3+2];
  }
  if (tid < KNB) sIdx[tid] = nbr[(size_t)n*KNB + tid];
  __syncthreads();
  if (tid < KNB){
    int i = sIdx[tid];
    sNb[tid][0] = pts[i*3+0] - pts[n*3+0];
    sNb[tid][1] = pts[i*3+1] - pts[n*3+1];
    sNb[tid][2] = pts[i*3+2] - pts[n*3+2];
    sFs[tid] = fsum[i];
  }
  __syncthreads();
  for (int j = tid; j < KNB*16; j += 128){
    int k = j >> 4, p = j & 15;
    float v = 0.0f;
    if (p < PKP){
      float dx = sNb[k][0]-sKP[p][0];
      float dy = sNb[k][1]-sKP[p][1];
      float dz = sNb[k][2]-sKP[p][2];
      float sq = dx*dx + dy*dy + dz*dz;
      v = fmaxf(1.0f - sqrtf(sq)*inv_ext, 0.0f);
    }
    sInfl[k][p] = v;
  }
  if (tid == 0){
    int c = 0;
    for (int k = 0; k < KNB; ++k) c += (sFs[k] > 0.0f) ? 1 : 0;
    invn[n] = 1.0f / (float)(c < 1 ? 1 : c);
  }
  __syncthreads();
  float w[PKP];
  #pragma unroll
  for (int p = 0; p < PKP; ++p) w[p] = 0.0f;
  for (int k = 0; k < KNB; ++k){
    float v = bf2f(feat[(size_t)sIdx[k]*128 + tid]);
    float4 i0 = *(const float4*)&sInfl[k][0];
    float4 i1 = *(const float4*)&sInfl[k][4];
    float4 i2 = *(const float4*)&sInfl[k][8];
    float4 i3 = *(const float4*)&sInfl[k][12];
    w[0]+=i0.x*v;  w[1]+=i0.y*v;  w[2]+=i0.z*v;  w[3]+=i0.w*v;
    w[4]+=i1.x*v;  w[5]+=i1.y*v;  w[6]+=i1.z*v;  w[7]+=i1.w*v;
    w[8]+=i2.x*v;  w[9]+=i2.y*v;  w[10]+=i2.z*v; w[11]+=i2.w*v;
    w[12]+=i3.x*v; w[13]+=i3.y*v; w[14]+=i3.z*v;
  }
  size_t obase = (size_t)blockIdx.x*1920 + tid;
  #pragma unroll
  for (int p = 0; p < PKP; ++p) wtd[obase + p*128] = f2bf(w[p]);
}

// --------------------------------------------------------------------------
// K4: kpf[base+r,128](bf16) = invn * (wtd_chunk[r,1920] @ kpw[1920,128](f32))
// --------------------------------------------------------------------------
__global__ __launch_bounds__(512) void k_conv(
    const unsigned short* __restrict__ wtd, const float* __restrict__ kpw,
    const float* __restrict__ invn, unsigned short* __restrict__ kpf, int base){
  __shared__ float sA[32][68];    // [kk][row], padded
  __shared__ float sB[32][128];   // [kk][col]
  int tid  = threadIdx.x;
  int lrow0 = blockIdx.x*64;               // local (chunk) row
  int rg = tid >> 5, cg = tid & 31;
  int r0 = rg*4, c0 = cg*4;
  float acc[4][4] = {};
  for (int kc = 0; kc < 1920; kc += 32){
    {
      int row = tid >> 3, kk0 = (tid & 7)*4;
      ushort4 u = *(const ushort4*)(wtd + (size_t)(lrow0+row)*1920 + kc + kk0);
      sA[kk0+0][row] = bf2f(u.x);
      sA[kk0+1][row] = bf2f(u.y);
      sA[kk0+2][row] = bf2f(u.z);
      sA[kk0+3][row] = bf2f(u.w);
    }
    #pragma unroll
    for (int t = 0; t < 2; ++t){
      int v = tid + t*512;
      int kk = v >> 5, cc = (v & 31)*4;
      *(float4*)&sB[kk][cc] = *(const float4*)&kpw[(size_t)(kc+kk)*128 + cc];
    }
    __syncthreads();
    #pragma unroll
    for (int kk = 0; kk < 32; ++kk){
      float4 a = *(const float4*)&sA[kk][r0];
      float4 b = *(const float4*)&sB[kk][c0];
      float av[4] = {a.x,a.y,a.z,a.w};
      float bv[4] = {b.x,b.y,b.z,b.w};
      #pragma unroll
      for (int i = 0; i < 4; ++i)
        #pragma unroll
        for (int j = 0; j < 4; ++j) acc[i][j] += av[i]*bv[j];
    }
    __syncthreads();
  }
  #pragma unroll
  for (int i = 0; i < 4; ++i){
    int grow = base + lrow0 + r0 + i;
    float sc = invn[grow];
    ushort4 o;
    o.x = f2bf(acc[i][0]*sc); o.y = f2bf(acc[i][1]*sc);
    o.z = f2bf(acc[i][2]*sc); o.w = f2bf(acc[i][3]*sc);
    *(ushort4*)&kpf[(size_t)grow*128 + c0] = o;
  }
}

// --------------------------------------------------------------------------
// K5: p1(bf16) = points[N,3] @ pos_w1[3,64] + b ; stats
// --------------------------------------------------------------------------
__global__ __launch_bounds__(256) void k_pos1(
    const float* __restrict__ pts, const float* __restrict__ w,
    const float* __restrict__ b, unsigned short* __restrict__ p1,
    float* __restrict__ stats){
  __shared__ float sSum[4][64], sSq[4][64];
  int tid = threadIdx.x;
  int c = tid & 63, grp = tid >> 6;
  int row0 = blockIdx.x*32;
  float w0 = w[c], w1 = w[64+c], w2 = w[128+c], bb = b[c];
  float ls = 0.0f, lq = 0.0f;
  for (int r = row0 + grp*8; r < row0 + grp*8 + 8; ++r){
    float x0 = pts[r*3+0], x1 = pts[r*3+1], x2 = pts[r*3+2];
    float y = bb + x0*w0 + x1*w1 + x2*w2;
    p1[(size_t)r*64 + c] = f2bf(y);
    ls += y; lq += y*y;
  }
  sSum[grp][c] = ls; sSq[grp][c] = lq;
  __syncthreads();
  if (grp == 0){
    atomicAdd(&stats[c],    sSum[0][c]+sSum[1][c]+sSum[2][c]+sSum[3][c]);
    atomicAdd(&stats[64+c], sSq[0][c]+sSq[1][c]+sSq[2][c]+sSq[3][c]);
  }
}

// --------------------------------------------------------------------------
// K6 generic: Y(bf16)[N,NOUT] = normin(X0|X1)(bf16) @ W[K0+K1,NOUT](f32)+bias
// --------------------------------------------------------------------------
__global__ __launch_bounds__(256) void k_mlp(
    const unsigned short* __restrict__ X0, const float* __restrict__ st0,
    const float* __restrict__ g0, const float* __restrict__ b0,
    int K0, int norm0,
    const unsigned short* __restrict__ X1, const float* __restrict__ st1,
    const float* __restrict__ g1, const float* __restrict__ b1,
    int K1,
    const float* __restrict__ W, const float* __restrict__ bias, int NOUT,
    unsigned short* __restrict__ Y, float* __restrict__ statsOut){
  __shared__ float sX[32][68];
  __shared__ float sW[32][64];
  __shared__ float sSc[32], sSh[32];
  __shared__ float sSum[64], sSq[64];
  int tid  = threadIdx.x;
  int row0 = blockIdx.x*64;
  int ct   = blockIdx.y*64;
  int KT   = K0 + K1;
  if (tid < 64){ sSum[tid] = 0.0f; sSq[tid] = 0.0f; }
  int rg = tid >> 4, cg = tid & 15;
  int r0 = rg*4, c0 = cg*4;
  float acc[4][4] = {};
  for (int kc = 0; kc < KT; kc += 32){
    int inSel = (kc < K0) ? 0 : 1;
    if (tid < 32){
      int ch; const float* st; const float* gg; const float* bb; int Ks; int nf;
      if (!inSel){ ch = kc + tid;      st = st0; gg = g0; bb = b0; Ks = K0; nf = norm0; }
      else       { ch = kc - K0 + tid; st = st1; gg = g1; bb = b1; Ks = K1; nf = 1; }
      if (nf){
        float s = st[ch], q = st[Ks+ch];
        float mean = s*INV_N, var = q*INV_N - mean*mean;
        float sc = gg[ch]*rsqrtf(var+BNEPS);
        sSc[tid] = sc; sSh[tid] = bb[ch] - mean*sc;
      } else { sSc[tid] = 1.0f; sSh[tid] = 0.0f; }
    }
    __syncthreads();
    int nf = inSel ? 1 : norm0;
    const unsigned short* Xp = inSel ? X1 : X0;
    int stride = inSel ? K1 : K0;
    int cb = inSel ? (kc - K0) : kc;
    #pragma unroll
    for (int t = 0; t < 2; ++t){
      int v = tid + t*256;
      int row = v >> 3, kk0 = (v & 7)*4;
      ushort4 x = *(const ushort4*)&Xp[(size_t)(row0+row)*stride + cb + kk0];
      unsigned short xs[4] = {x.x, x.y, x.z, x.w};
      #pragma unroll
      for (int j = 0; j < 4; ++j){
        float xv = bf2f(xs[j]);
        if (nf){ xv = xv*sSc[kk0+j] + sSh[kk0+j]; xv = lrelu(xv); }
        sX[kk0+j][row] = xv;
      }
    }
    #pragma unroll
    for (int t = 0; t < 2; ++t){
      int v = tid + t*256;
      int kk = v >> 4, cc = (v & 15)*4;
      *(float4*)&sW[kk][cc] = *(const float4*)&W[(size_t)(kc+kk)*NOUT + ct + cc];
    }
    __syncthreads();
    #pragma unroll
    for (int kk = 0; kk < 32; ++kk){
      float4 a = *(const float4*)&sX[kk][r0];
      float4 b = *(const float4*)&sW[kk][c0];
      float av[4] = {a.x,a.y,a.z,a.w};
      float bv[4] = {b.x,b.y,b.z,b.w};
      #pragma unroll
      for (int i = 0; i < 4; ++i)
        #pragma unroll
        for (int j = 0; j < 4; ++j) acc[i][j] += av[i]*bv[j];
    }
    __syncthreads();
  }
  float bj[4];
  #pragma unroll
  for (int j = 0; j < 4; ++j) bj[j] = bias[ct + c0 + j];
  float cs[4] = {0,0,0,0}, cq[4] = {0,0,0,0};
  #pragma unroll
  for (int i = 0; i < 4; ++i){
    float v0 = acc[i][0]+bj[0], v1 = acc[i][1]+bj[1];
    float v2 = acc[i][2]+bj[2], v3 = acc[i][3]+bj[3];
    ushort4 o; o.x=f2bf(v0); o.y=f2bf(v1); o.z=f2bf(v2); o.w=f2bf(v3);
    *(ushort4*)&Y[(size_t)(row0+r0+i)*NOUT + ct + c0] = o;
    cs[0]+=v0; cs[1]+=v1; cs[2]+=v2; cs[3]+=v3;
    cq[0]+=v0*v0; cq[1]+=v1*v1; cq[2]+=v2*v2; cq[3]+=v3*v3;
  }
  #pragma unroll
  for (int j = 0; j < 4; ++j){
    atomicAdd(&sSum[c0+j], cs[j]);
    atomicAdd(&sSq[c0+j],  cq[j]);
  }
  __syncthreads();
  if (tid < 64){
    atomicAdd(&statsOut[ct+tid],      sSum[tid]);
    atomicAdd(&statsOut[NOUT+ct+tid], sSq[tid]);
  }
}

// --------------------------------------------------------------------------
// K7 head: out[n] = f32(sigmoid( sum_c lrelu(bn(H[n,c]))*w2[c] + b2 ))
// --------------------------------------------------------------------------
__global__ __launch_bounds__(256) void k_head(
    const unsigned short* __restrict__ H, const float* __restrict__ stats,
    const float* __restrict__ g, const float* __restrict__ b,
    const float* __restrict__ w2, const float* __restrict__ b2,
    float* __restrict__ out, int Cdim){
  int wid  = (int)((blockIdx.x*256 + threadIdx.x) >> 6);
  int lane = threadIdx.x & 63;
  if (wid >= NPTS) return;
  float acc = 0.0f;
  for (int c = lane; c < Cdim; c += 64){
    float su = stats[c], sq = stats[Cdim+c];
    float mean = su*INV_N, var = sq*INV_N - mean*mean;
    float sc = g[c]*rsqrtf(var+BNEPS), sh = b[c]-mean*sc;
    float h = lrelu(bf2f(H[(size_t)wid*Cdim + c])*sc + sh);
    acc += h * w2[c];
  }
  #pragma unroll
  for (int o = 32; o; o >>= 1) acc += __shfl_down(acc, o, 64);
  if (lane == 0){
    float x = acc + b2[0];
    out[wid] = 1.0f/(1.0f + expf(-x));
  }
}

// --------------------------------------------------------------------------
// K8: neighbors_index passthrough as float32
// --------------------------------------------------------------------------
__global__ __launch_bounds__(256) void k_idx(
    const int* __restrict__ nbr, float* __restrict__ o){
  int i = blockIdx.x*256 + threadIdx.x;           // grid sized exactly
  int4 v = ((const int4*)nbr)[i];
  ((float4*)o)[i] = make_float4((float)v.x,(float)v.y,(float)v.z,(float)v.w);
}

// --------------------------------------------------------------------------
extern "C" void kernel_launch(void* const* d_in, const int* in_sizes, int n_in,
                              void* d_out, int out_size, void* d_ws, size_t ws_size,
                              hipStream_t stream) {
  const float* pts    = (const float*)d_in[0];
  const float* cov    = (const float*)d_in[1];
  const int*   nbr    = (const int*)  d_in[2];
  const float* pre_w  = (const float*)d_in[3];
  const float* pre_b  = (const float*)d_in[4];
  const float* pre_g  = (const float*)d_in[5];
  const float* pre_bb = (const float*)d_in[6];
  const float* kp     = (const float*)d_in[7];
  const float* kpw    = (const float*)d_in[8];
  const float* pos_w1 = (const float*)d_in[9];
  const float* pos_b1 = (const float*)d_in[10];
  const float* pos_g1 = (const float*)d_in[11];
  const float* pos_bb1= (const float*)d_in[12];
  const float* pos_w2 = (const float*)d_in[13];
  const float* pos_b2 = (const float*)d_in[14];
  const float* pos_g2 = (const float*)d_in[15];
  const float* pos_bb2= (const float*)d_in[16];
  const float* agg_w1 = (const float*)d_in[17];
  const float* agg_b1 = (const float*)d_in[18];
  const float* agg_g1 = (const float*)d_in[19];
  const float* agg_bb1= (const float*)d_in[20];
  const float* agg_w2 = (const float*)d_in[21];
  const float* agg_b2 = (const float*)d_in[22];
  const float* agg_g2 = (const float*)d_in[23];
  const float* agg_bb2= (const float*)d_in[24];
  const float* keep_w1= (const float*)d_in[25];
  const float* keep_b1= (const float*)d_in[26];
  const float* keep_g = (const float*)d_in[27];
  const float* keep_bb= (const float*)d_in[28];
  const float* keep_w2= (const float*)d_in[29];
  const float* keep_b2= (const float*)d_in[30];
  const float* uniq_w1= (const float*)d_in[31];
  const float* uniq_b1= (const float*)d_in[32];
  const float* uniq_g = (const float*)d_in[33];
  const float* uniq_bb= (const float*)d_in[34];
  const float* uniq_w2= (const float*)d_in[35];
  const float* uniq_b2= (const float*)d_in[36];

  float* out = (float*)d_out;     // f32 [match(N) | unique(N) | idx(N*K)]

  // ---- ws layout (bytes), bf16 activations, bounded by ws_size ----
  char* wsb = (char*)d_ws;
  size_t off = 0;
  float* stats = (float*)(wsb + off); off += 4096*4;                 // 16 KB
  float* fsum  = (float*)(wsb + off); off += (size_t)NPTS*4;         // 160 KB
  float* invn  = (float*)(wsb + off); off += (size_t)NPTS*4;         // 160 KB
  unsigned short* kpf  = (unsigned short*)(wsb + off); off += (size_t)NPTS*128*2;
  unsigned short* feat = (unsigned short*)(wsb + off); off += (size_t)NPTS*128*2;
  unsigned short* p2   = (unsigned short*)(wsb + off); off += (size_t)NPTS*256*2;
  unsigned short* a2   = (unsigned short*)(wsb + off); off += (size_t)NPTS*256*2;
  unsigned short* a1   = (unsigned short*)(wsb + off); off += (size_t)NPTS*256*2;
  // aliases into dead regions:
  unsigned short* preact = p2;            // preact dead before p2 is written
  unsigned short* p1 = feat;              // feat dead after kpconv chunks
  unsigned short* k1 = a1;                // a1 dead after agg2
  unsigned short* u1 = a1 + (size_t)NPTS*64;
  // chunked weighted buffer in remaining space
  unsigned short* wtd = (unsigned short*)(wsb + off);
  size_t rem = (ws_size > off) ? (ws_size - off) : 0;
  long long chF = (long long)(rem / (1920*2));
  int CH = (int)((chF / 64) * 64);
  if (CH < 64) CH = 64;
  if (CH > NPTS) CH = NPTS;

  const double kpe = 1.0 / (cbrt(15.0) - 1.0) * 1.5;   // KP_EXTENT
  const float inv_ext = (float)(1.0 / kpe);

  hipMemsetAsync(stats, 0, 2304*sizeof(float), stream);

  // pre layer (preact aliases p2 region; consumed before p2 write)
  k_pre<<<1250, 256, 0, stream>>>(cov, pre_w, pre_b, preact, stats + 0);
  k_prenorm<<<10000, 256, 0, stream>>>(preact, stats + 0, pre_g, pre_bb, feat, fsum);

  // KPConv in chunks of CH rows (CH multiple of 64; 40000 = 625*64)
  for (int base = 0; base < NPTS; base += CH){
    int rows = (NPTS - base < CH) ? (NPTS - base) : CH;
    k_kpconv<<<rows, 128, 0, stream>>>(pts, nbr, kp, feat, fsum, wtd, invn,
                                       inv_ext, base);
    k_conv<<<rows/64, 512, 0, stream>>>(wtd, kpw, invn, kpf, base);
  }

  // pos branch (p1 aliases feat: feat dead now)
  k_pos1<<<1250, 256, 0, stream>>>(pts, pos_w1, pos_b1, p1, stats + 256);
  k_mlp<<<dim3(625,4), 256, 0, stream>>>(
      p1, stats + 256, pos_g1, pos_bb1, 64, 1,
      nullptr, nullptr, nullptr, nullptr, 0,
      pos_w2, pos_b2, 256, p2, stats + 384);

  // agg branch
  k_mlp<<<dim3(625,4), 256, 0, stream>>>(
      kpf, nullptr, nullptr, nullptr, 128, 0,
      nullptr, nullptr, nullptr, nullptr, 0,
      agg_w1, agg_b1, 256, a1, stats + 896);
  k_mlp<<<dim3(625,4), 256, 0, stream>>>(
      a1, stats + 896, agg_g1, agg_bb1, 256, 1,
      nullptr, nullptr, nullptr, nullptr, 0,
      agg_w2, agg_b2, 256, a2, stats + 1408);

  // keep head (k1 aliases a1: a1 dead after agg2)
  k_mlp<<<dim3(625,1), 256, 0, stream>>>(
      a2, stats + 1408, agg_g2, agg_bb2, 256, 1,
      nullptr, nullptr, nullptr, nullptr, 0,
      keep_w1, keep_b1, 64, k1, stats + 1920);
  k_head<<<10000, 256, 0, stream>>>(k1, stats + 1920, keep_g, keep_bb,
                                    keep_w2, keep_b2, out, 64);

  // uniq head (concat [p2 norm, a2 norm]; u1 aliases a1+N*64)
  k_mlp<<<dim3(625,2), 256, 0, stream>>>(
      p2, stats + 384, pos_g2, pos_bb2, 256, 1,
      a2, stats + 1408, agg_g2, agg_bb2, 256,
      uniq_w1, uniq_b1, 128, u1, stats + 2048);
  k_head<<<10000, 256, 0, stream>>>(u1, stats + 2048, uniq_g, uniq_bb,
                                    uniq_w2, uniq_b2, out + NPTS, 128);

  // neighbors_index passthrough (f32 values)
  k_idx<<<1250, 256, 0, stream>>>(nbr, out + 2*NPTS);
}

// Round 5
// 532.813 us; speedup vs baseline: 1.5863x; 1.5863x over previous
//
#include <hip/hip_runtime.h>
#include <math.h>

// ---------------------------------------------------------------------------
// BimodalCompressor: KPConv point network (round 5)
// MFMA bf16 GEMMs (conv + all MLP layers), fp32 stats/epilogues, f32 outputs.
// N=40000 pts, K=32 neighbors, P=15 kernel pts, C=128 channels.
// BN: training mode, biased var, eps=1e-5. LeakyReLU slope 0.01.
// ---------------------------------------------------------------------------

#define NPTS 40000
#define KNB  32
#define PKP  15
#define SLOPE 0.01f
#define BNEPS 1e-5f
#define INV_N (1.0f/40000.0f)

typedef __attribute__((ext_vector_type(8))) short bf16x8;
typedef __attribute__((ext_vector_type(4))) float f32x4;

__device__ __forceinline__ float lrelu(float x){ return x >= 0.0f ? x : SLOPE*x; }
__device__ __forceinline__ unsigned short f2bf(float f){
  unsigned int b = __float_as_uint(f);
  b += 0x7fffu + ((b>>16)&1u);            // round-to-nearest-even
  return (unsigned short)(b>>16);
}
__device__ __forceinline__ float bf2f(unsigned short u){
  return __uint_as_float(((unsigned int)u)<<16);
}

// --------------------------------------------------------------------------
// K0: weight prep: Wt[n*K+k] = bf16(W[k*N+n])   (one launch per weight)
// --------------------------------------------------------------------------
__global__ __launch_bounds__(256) void k_wprep(
    const float* __restrict__ W, int K, int N, unsigned short* __restrict__ Wt){
  int i = blockIdx.x*256 + threadIdx.x;
  if (i >= K*N) return;
  int k = i / N, n = i - k*N;
  Wt[(size_t)n*K + k] = f2bf(W[i]);
}

// --------------------------------------------------------------------------
// K1: preact(bf16) = cov[N,9] @ pre_w[9,128] + pre_b ; stats (fp32 atomics)
// --------------------------------------------------------------------------
__global__ __launch_bounds__(256) void k_pre(
    const float* __restrict__ cov, const float* __restrict__ w,
    const float* __restrict__ b, unsigned short* __restrict__ preact,
    float* __restrict__ stats){
  __shared__ float sW[9*128];
  __shared__ float sX[32*9];
  __shared__ float sSum[2][128], sSq[2][128];
  int tid = threadIdx.x;
  int row0 = blockIdx.x*32;
  for (int i = tid; i < 9*128; i += 256) sW[i] = w[i];
  for (int i = tid; i < 32*9;  i += 256) sX[i] = cov[row0*9 + i];
  __syncthreads();
  int c = tid & 127, h = tid >> 7;
  float bias = b[c];
  float ls = 0.0f, lq = 0.0f;
  for (int r = h*16; r < h*16+16; ++r){
    float acc = bias;
    #pragma unroll
    for (int i = 0; i < 9; ++i) acc += sX[r*9+i]*sW[i*128+c];
    preact[(size_t)(row0+r)*128 + c] = f2bf(acc);
    ls += acc; lq += acc*acc;
  }
  sSum[h][c] = ls; sSq[h][c] = lq;
  __syncthreads();
  if (h == 0){
    atomicAdd(&stats[c],     sSum[0][c]+sSum[1][c]);
    atomicAdd(&stats[128+c], sSq[0][c]+sSq[1][c]);
  }
}

// --------------------------------------------------------------------------
// K2: feat(bf16) = lrelu(bn(preact)) ; fsum[n] (fp32)
// --------------------------------------------------------------------------
__global__ __launch_bounds__(256) void k_prenorm(
    const unsigned short* __restrict__ preact, const float* __restrict__ stats,
    const float* __restrict__ g, const float* __restrict__ b,
    unsigned short* __restrict__ feat, float* __restrict__ fsum){
  int wid  = (int)((blockIdx.x*256 + threadIdx.x) >> 6);
  int lane = threadIdx.x & 63;
  if (wid >= NPTS) return;
  float su = stats[lane], sq = stats[128+lane];
  float mean = su*INV_N, var = sq*INV_N - mean*mean;
  float s0 = g[lane]*rsqrtf(var+BNEPS), h0 = b[lane]-mean*s0;
  su = stats[64+lane]; sq = stats[192+lane];
  mean = su*INV_N; var = sq*INV_N - mean*mean;
  float s1 = g[64+lane]*rsqrtf(var+BNEPS), h1 = b[64+lane]-mean*s1;
  size_t off = (size_t)wid*128;
  float f0 = lrelu(bf2f(preact[off+lane])*s0+h0);
  float f1 = lrelu(bf2f(preact[off+64+lane])*s1+h1);
  feat[off+lane]    = f2bf(f0);
  feat[off+64+lane] = f2bf(f1);
  float t = f0 + f1;
  #pragma unroll
  for (int o = 32; o; o >>= 1) t += __shfl_down(t, o, 64);
  if (lane == 0) fsum[wid] = t;
}

// --------------------------------------------------------------------------
// K3: per point n in [base, base+rows): influences [K,P], gather bf16 feats,
// wtd_chunk[(n-base),p,c] = bf16( sum_k infl[k,p]*feat[idx[k],c] ) ; invn[n]
// --------------------------------------------------------------------------
__global__ __launch_bounds__(128) void k_kpconv(
    const float* __restrict__ pts, const int* __restrict__ nbr,
    const float* __restrict__ kp, const unsigned short* __restrict__ feat,
    const float* __restrict__ fsum, unsigned short* __restrict__ wtd,
    float* __restrict__ invn, float inv_ext, int base){
  int n   = base + blockIdx.x;
  int tid = threadIdx.x;
  __shared__ int   sIdx[KNB];
  __shared__ float sNb[KNB][3];
  __shared__ float sFs[KNB];
  __shared__ float sKP[16][3];
  __shared__ float sInfl[KNB][16];   // padded P 15->16 for float4 reads
  if (tid < PKP){
    sKP[tid][0]=kp[tid*3+0]; sKP[tid][1]=kp[tid*3+1]; sKP[tid][2]=kp[tid*3+2];
  }
  if (tid < KNB) sIdx[tid] = nbr[(size_t)n*KNB + tid];
  __syncthreads();
  if (tid < KNB){
    int i = sIdx[tid];
    sNb[tid][0] = pts[i*3+0] - pts[n*3+0];
    sNb[tid][1] = pts[i*3+1] - pts[n*3+1];
    sNb[tid][2] = pts[i*3+2] - pts[n*3+2];
    sFs[tid] = fsum[i];
  }
  __syncthreads();
  for (int j = tid; j < KNB*16; j += 128){
    int k = j >> 4, p = j & 15;
    float v = 0.0f;
    if (p < PKP){
      float dx = sNb[k][0]-sKP[p][0];
      float dy = sNb[k][1]-sKP[p][1];
      float dz = sNb[k][2]-sKP[p][2];
      float sq = dx*dx + dy*dy + dz*dz;
      v = fmaxf(1.0f - sqrtf(sq)*inv_ext, 0.0f);
    }
    sInfl[k][p] = v;
  }
  if (tid == 0){
    int c = 0;
    for (int k = 0; k < KNB; ++k) c += (sFs[k] > 0.0f) ? 1 : 0;
    invn[n] = 1.0f / (float)(c < 1 ? 1 : c);
  }
  __syncthreads();
  float w[PKP];
  #pragma unroll
  for (int p = 0; p < PKP; ++p) w[p] = 0.0f;
  for (int k = 0; k < KNB; ++k){
    float v = bf2f(feat[(size_t)sIdx[k]*128 + tid]);
    float4 i0 = *(const float4*)&sInfl[k][0];
    float4 i1 = *(const float4*)&sInfl[k][4];
    float4 i2 = *(const float4*)&sInfl[k][8];
    float4 i3 = *(const float4*)&sInfl[k][12];
    w[0]+=i0.x*v;  w[1]+=i0.y*v;  w[2]+=i0.z*v;  w[3]+=i0.w*v;
    w[4]+=i1.x*v;  w[5]+=i1.y*v;  w[6]+=i1.z*v;  w[7]+=i1.w*v;
    w[8]+=i2.x*v;  w[9]+=i2.y*v;  w[10]+=i2.z*v; w[11]+=i2.w*v;
    w[12]+=i3.x*v; w[13]+=i3.y*v; w[14]+=i3.z*v;
  }
  size_t obase = (size_t)blockIdx.x*1920 + tid;
  #pragma unroll
  for (int p = 0; p < PKP; ++p) wtd[obase + p*128] = f2bf(w[p]);
}

// --------------------------------------------------------------------------
// K4 MFMA GEMM: Y(bf16)[M,NOUT] = epi( norm(X0|X1)[M,KT](bf16) @ Wt + bias )
// Wt is pre-transposed bf16 [NOUT][KT]. Tile 64x64, 256 thr (4 waves, one
// 16-row band each), BK=64, XOR-swizzled LDS. epi: +bias, *rowscale, stats.
// v_mfma_f32_16x16x32_bf16 layouts (m89-verified):
//   A: lane l elem j = A[l&15][8*(l>>4)+j]; B: lane l elem j = B[8*(l>>4)+j][l&15]
//   D: lane l reg r  = D[4*(l>>4)+r][l&15]
// --------------------------------------------------------------------------
__global__ __launch_bounds__(256) void k_gemm(
    const unsigned short* __restrict__ X0, const float* __restrict__ st0,
    const float* __restrict__ g0, const float* __restrict__ b0,
    int K0, int norm0,
    const unsigned short* __restrict__ X1, const float* __restrict__ st1,
    const float* __restrict__ g1, const float* __restrict__ b1, int K1,
    const unsigned short* __restrict__ Wt, const float* __restrict__ bias,
    int NOUT, const float* __restrict__ rowscale, int rowbase,
    unsigned short* __restrict__ Y, float* __restrict__ statsOut){
  __shared__ unsigned short sA[64*64];
  __shared__ unsigned short sB[64*64];
  __shared__ float sSc[64], sSh[64];
  __shared__ float sSum[64], sSq[64];
  int tid = threadIdx.x;
  int row0 = blockIdx.x*64;
  int ct   = blockIdx.y*64;
  int w = tid >> 6, l = tid & 63;
  int KT = K0 + K1;
  if (tid < 64){ sSum[tid] = 0.0f; sSq[tid] = 0.0f; }
  f32x4 acc[4] = {};
  for (int kc = 0; kc < KT; kc += 64){
    bool sel1 = (kc >= K0);
    const unsigned short* Xp = sel1 ? X1 : X0;
    int Ks = sel1 ? K1 : K0;
    int cb = sel1 ? kc - K0 : kc;
    int nf = sel1 ? 1 : norm0;
    if (tid < 64){
      if (nf){
        const float* st = sel1 ? st1 : st0;
        const float* gg = sel1 ? g1 : g0;
        const float* bb = sel1 ? b1 : b0;
        int ch = cb + tid;
        float s = st[ch], q = st[Ks+ch];
        float mean = s*INV_N, var = q*INV_N - mean*mean;
        float sc = gg[ch]*rsqrtf(var+BNEPS);
        sSc[tid] = sc; sSh[tid] = bb[ch] - mean*sc;
      }
    }
    __syncthreads();
    // stage A (64 rows x 64 k) and B (64 cols x 64 k), 2 passes of 32
    #pragma unroll
    for (int p = 0; p < 2; ++p){
      int r = (tid >> 3) + p*32;
      int k0 = (tid & 7)*8;
      uint4 v = *(const uint4*)(Xp + (size_t)(row0+r)*Ks + cb + k0);
      if (nf){
        unsigned short e[8] = {(unsigned short)(v.x&0xffff),(unsigned short)(v.x>>16),
                               (unsigned short)(v.y&0xffff),(unsigned short)(v.y>>16),
                               (unsigned short)(v.z&0xffff),(unsigned short)(v.z>>16),
                               (unsigned short)(v.w&0xffff),(unsigned short)(v.w>>16)};
        unsigned short o[8];
        #pragma unroll
        for (int j = 0; j < 8; ++j){
          float f = lrelu(bf2f(e[j])*sSc[k0+j] + sSh[k0+j]);
          o[j] = f2bf(f);
        }
        v.x = (uint)o[0] | ((uint)o[1]<<16);
        v.y = (uint)o[2] | ((uint)o[3]<<16);
        v.z = (uint)o[4] | ((uint)o[5]<<16);
        v.w = (uint)o[6] | ((uint)o[7]<<16);
      }
      int byteA = (r*128 + k0*2) ^ ((r&7)<<4);
      *(uint4*)((char*)sA + byteA) = v;
      uint4 vb = *(const uint4*)(Wt + (size_t)(ct+r)*KT + kc + k0);
      int byteB = (r*128 + k0*2) ^ ((r&7)<<4);
      *(uint4*)((char*)sB + byteB) = vb;
    }
    __syncthreads();
    // compute: wave w owns rows [w*16, w*16+16)
    int rowA = w*16 + (l & 15);
    #pragma unroll
    for (int m = 0; m < 2; ++m){
      int ka = m*32 + (l >> 4)*8;
      int byteA = (rowA*128 + ka*2) ^ ((rowA&7)<<4);
      bf16x8 af = *(const bf16x8*)((const char*)sA + byteA);
      #pragma unroll
      for (int cf = 0; cf < 4; ++cf){
        int colB = cf*16 + (l & 15);
        int byteB = (colB*128 + ka*2) ^ ((colB&7)<<4);
        bf16x8 bfr = *(const bf16x8*)((const char*)sB + byteB);
        acc[cf] = __builtin_amdgcn_mfma_f32_16x16x32_bf16(af, bfr, acc[cf], 0, 0, 0);
      }
    }
    __syncthreads();
  }
  // epilogue
  float cs[4] = {0,0,0,0}, cq[4] = {0,0,0,0};
  #pragma unroll
  for (int cf = 0; cf < 4; ++cf){
    int col = ct + cf*16 + (l & 15);
    float bj = bias ? bias[col] : 0.0f;
    #pragma unroll
    for (int r = 0; r < 4; ++r){
      int grow = rowbase + row0 + w*16 + (l >> 4)*4 + r;
      float v = acc[cf][r] + bj;
      if (rowscale) v *= rowscale[grow];
      Y[(size_t)grow*NOUT + col] = f2bf(v);
      cs[cf] += v; cq[cf] += v*v;
    }
  }
  if (statsOut){
    #pragma unroll
    for (int cf = 0; cf < 4; ++cf){
      atomicAdd(&sSum[cf*16 + (l&15)], cs[cf]);
      atomicAdd(&sSq[cf*16 + (l&15)],  cq[cf]);
    }
    __syncthreads();
    if (tid < 64){
      atomicAdd(&statsOut[ct+tid],      sSum[tid]);
      atomicAdd(&statsOut[NOUT+ct+tid], sSq[tid]);
    }
  }
}

// --------------------------------------------------------------------------
// K5: p1(bf16) = points[N,3] @ pos_w1[3,64] + b ; stats
// --------------------------------------------------------------------------
__global__ __launch_bounds__(256) void k_pos1(
    const float* __restrict__ pts, const float* __restrict__ w,
    const float* __restrict__ b, unsigned short* __restrict__ p1,
    float* __restrict__ stats){
  __shared__ float sSum[4][64], sSq[4][64];
  int tid = threadIdx.x;
  int c = tid & 63, grp = tid >> 6;
  int row0 = blockIdx.x*32;
  float w0 = w[c], w1 = w[64+c], w2 = w[128+c], bb = b[c];
  float ls = 0.0f, lq = 0.0f;
  for (int r = row0 + grp*8; r < row0 + grp*8 + 8; ++r){
    float x0 = pts[r*3+0], x1 = pts[r*3+1], x2 = pts[r*3+2];
    float y = bb + x0*w0 + x1*w1 + x2*w2;
    p1[(size_t)r*64 + c] = f2bf(y);
    ls += y; lq += y*y;
  }
  sSum[grp][c] = ls; sSq[grp][c] = lq;
  __syncthreads();
  if (grp == 0){
    atomicAdd(&stats[c],    sSum[0][c]+sSum[1][c]+sSum[2][c]+sSum[3][c]);
    atomicAdd(&stats[64+c], sSq[0][c]+sSq[1][c]+sSq[2][c]+sSq[3][c]);
  }
}

// --------------------------------------------------------------------------
// K7 head: out[n] = f32(sigmoid( sum_c lrelu(bn(H[n,c]))*w2[c] + b2 ))
// --------------------------------------------------------------------------
__global__ __launch_bounds__(256) void k_head(
    const unsigned short* __restrict__ H, const float* __restrict__ stats,
    const float* __restrict__ g, const float* __restrict__ b,
    const float* __restrict__ w2, const float* __restrict__ b2,
    float* __restrict__ out, int Cdim){
  int wid  = (int)((blockIdx.x*256 + threadIdx.x) >> 6);
  int lane = threadIdx.x & 63;
  if (wid >= NPTS) return;
  float acc = 0.0f;
  for (int c = lane; c < Cdim; c += 64){
    float su = stats[c], sq = stats[Cdim+c];
    float mean = su*INV_N, var = sq*INV_N - mean*mean;
    float sc = g[c]*rsqrtf(var+BNEPS), sh = b[c]-mean*sc;
    float h = lrelu(bf2f(H[(size_t)wid*Cdim + c])*sc + sh);
    acc += h * w2[c];
  }
  #pragma unroll
  for (int o = 32; o; o >>= 1) acc += __shfl_down(acc, o, 64);
  if (lane == 0){
    float x = acc + b2[0];
    out[wid] = 1.0f/(1.0f + expf(-x));
  }
}

// --------------------------------------------------------------------------
// K8: neighbors_index passthrough as float32
// --------------------------------------------------------------------------
__global__ __launch_bounds__(256) void k_idx(
    const int* __restrict__ nbr, float* __restrict__ o){
  int i = blockIdx.x*256 + threadIdx.x;           // grid sized exactly
  int4 v = ((const int4*)nbr)[i];
  ((float4*)o)[i] = make_float4((float)v.x,(float)v.y,(float)v.z,(float)v.w);
}

// --------------------------------------------------------------------------
extern "C" void kernel_launch(void* const* d_in, const int* in_sizes, int n_in,
                              void* d_out, int out_size, void* d_ws, size_t ws_size,
                              hipStream_t stream) {
  const float* pts    = (const float*)d_in[0];
  const float* cov    = (const float*)d_in[1];
  const int*   nbr    = (const int*)  d_in[2];
  const float* pre_w  = (const float*)d_in[3];
  const float* pre_b  = (const float*)d_in[4];
  const float* pre_g  = (const float*)d_in[5];
  const float* pre_bb = (const float*)d_in[6];
  const float* kp     = (const float*)d_in[7];
  const float* kpw    = (const float*)d_in[8];
  const float* pos_w1 = (const float*)d_in[9];
  const float* pos_b1 = (const float*)d_in[10];
  const float* pos_g1 = (const float*)d_in[11];
  const float* pos_bb1= (const float*)d_in[12];
  const float* pos_w2 = (const float*)d_in[13];
  const float* pos_b2 = (const float*)d_in[14];
  const float* pos_g2 = (const float*)d_in[15];
  const float* pos_bb2= (const float*)d_in[16];
  const float* agg_w1 = (const float*)d_in[17];
  const float* agg_b1 = (const float*)d_in[18];
  const float* agg_g1 = (const float*)d_in[19];
  const float* agg_bb1= (const float*)d_in[20];
  const float* agg_w2 = (const float*)d_in[21];
  const float* agg_b2 = (const float*)d_in[22];
  const float* agg_g2 = (const float*)d_in[23];
  const float* agg_bb2= (const float*)d_in[24];
  const float* keep_w1= (const float*)d_in[25];
  const float* keep_b1= (const float*)d_in[26];
  const float* keep_g = (const float*)d_in[27];
  const float* keep_bb= (const float*)d_in[28];
  const float* keep_w2= (const float*)d_in[29];
  const float* keep_b2= (const float*)d_in[30];
  const float* uniq_w1= (const float*)d_in[31];
  const float* uniq_b1= (const float*)d_in[32];
  const float* uniq_g = (const float*)d_in[33];
  const float* uniq_bb= (const float*)d_in[34];
  const float* uniq_w2= (const float*)d_in[35];
  const float* uniq_b2= (const float*)d_in[36];

  float* out = (float*)d_out;     // f32 [match(N) | unique(N) | idx(N*K)]

  // ---- ws layout (bytes), bf16 activations, bounded by ws_size ----
  char* wsb = (char*)d_ws;
  size_t off = 0;
  float* stats = (float*)(wsb + off); off += 4096*4;                 // 16 KB
  // transposed bf16 weights
  unsigned short* kpwT   = (unsigned short*)(wsb + off); off += (size_t)1920*128*2;
  unsigned short* posw2T = (unsigned short*)(wsb + off); off += (size_t)64*256*2;
  unsigned short* aggw1T = (unsigned short*)(wsb + off); off += (size_t)128*256*2;
  unsigned short* aggw2T = (unsigned short*)(wsb + off); off += (size_t)256*256*2;
  unsigned short* keepw1T= (unsigned short*)(wsb + off); off += (size_t)256*64*2;
  unsigned short* uniqw1T= (unsigned short*)(wsb + off); off += (size_t)512*128*2;
  float* fsum  = (float*)(wsb + off); off += (size_t)NPTS*4;         // 160 KB
  float* invn  = (float*)(wsb + off); off += (size_t)NPTS*4;         // 160 KB
  unsigned short* kpf  = (unsigned short*)(wsb + off); off += (size_t)NPTS*128*2;
  unsigned short* feat = (unsigned short*)(wsb + off); off += (size_t)NPTS*128*2;
  unsigned short* p2   = (unsigned short*)(wsb + off); off += (size_t)NPTS*256*2;
  unsigned short* a2   = (unsigned short*)(wsb + off); off += (size_t)NPTS*256*2;
  unsigned short* a1   = (unsigned short*)(wsb + off); off += (size_t)NPTS*256*2;
  // aliases into dead regions:
  unsigned short* preact = p2;            // preact dead before p2 is written
  unsigned short* p1 = feat;              // feat dead after kpconv chunks
  unsigned short* k1 = a1;                // a1 dead after agg2
  unsigned short* u1 = a1 + (size_t)NPTS*64;
  // chunked weighted buffer in remaining space
  unsigned short* wtd = (unsigned short*)(wsb + off);
  size_t rem = (ws_size > off) ? (ws_size - off) : 0;
  long long chF = (long long)(rem / (1920*2));
  int CH = (int)((chF / 64) * 64);
  if (CH < 64) CH = 64;
  if (CH > NPTS) CH = NPTS;

  const double kpe = 1.0 / (cbrt(15.0) - 1.0) * 1.5;   // KP_EXTENT
  const float inv_ext = (float)(1.0 / kpe);

  hipMemsetAsync(stats, 0, 2304*sizeof(float), stream);

  // weight prep (f32 -> bf16, transposed)
  k_wprep<<<(1920*128+255)/256, 256, 0, stream>>>(kpw,     1920, 128, kpwT);
  k_wprep<<<(64*256+255)/256,   256, 0, stream>>>(pos_w2,  64,   256, posw2T);
  k_wprep<<<(128*256+255)/256,  256, 0, stream>>>(agg_w1,  128,  256, aggw1T);
  k_wprep<<<(256*256+255)/256,  256, 0, stream>>>(agg_w2,  256,  256, aggw2T);
  k_wprep<<<(256*64+255)/256,   256, 0, stream>>>(keep_w1, 256,  64,  keepw1T);
  k_wprep<<<(512*128+255)/256,  256, 0, stream>>>(uniq_w1, 512,  128, uniqw1T);

  // pre layer (preact aliases p2 region; consumed before p2 write)
  k_pre<<<1250, 256, 0, stream>>>(cov, pre_w, pre_b, preact, stats + 0);
  k_prenorm<<<10000, 256, 0, stream>>>(preact, stats + 0, pre_g, pre_bb, feat, fsum);

  // KPConv in chunks of CH rows (CH multiple of 64; 40000 = 625*64)
  for (int base = 0; base < NPTS; base += CH){
    int rows = (NPTS - base < CH) ? (NPTS - base) : CH;
    k_kpconv<<<rows, 128, 0, stream>>>(pts, nbr, kp, feat, fsum, wtd, invn,
                                       inv_ext, base);
    k_gemm<<<dim3(rows/64, 2), 256, 0, stream>>>(
        wtd, nullptr, nullptr, nullptr, 1920, 0,
        nullptr, nullptr, nullptr, nullptr, 0,
        kpwT, nullptr, 128, invn, base, kpf, nullptr);
  }

  // pos branch (p1 aliases feat: feat dead now)
  k_pos1<<<1250, 256, 0, stream>>>(pts, pos_w1, pos_b1, p1, stats + 256);
  k_gemm<<<dim3(625, 4), 256, 0, stream>>>(
      p1, stats + 256, pos_g1, pos_bb1, 64, 1,
      nullptr, nullptr, nullptr, nullptr, 0,
      posw2T, pos_b2, 256, nullptr, 0, p2, stats + 384);

  // agg branch
  k_gemm<<<dim3(625, 4), 256, 0, stream>>>(
      kpf, nullptr, nullptr, nullptr, 128, 0,
      nullptr, nullptr, nullptr, nullptr, 0,
      aggw1T, agg_b1, 256, nullptr, 0, a1, stats + 896);
  k_gemm<<<dim3(625, 4), 256, 0, stream>>>(
      a1, stats + 896, agg_g1, agg_bb1, 256, 1,
      nullptr, nullptr, nullptr, nullptr, 0,
      aggw2T, agg_b2, 256, nullptr, 0, a2, stats + 1408);

  // keep head (k1 aliases a1: a1 dead after agg2)
  k_gemm<<<dim3(625, 1), 256, 0, stream>>>(
      a2, stats + 1408, agg_g2, agg_bb2, 256, 1,
      nullptr, nullptr, nullptr, nullptr, 0,
      keepw1T, keep_b1, 64, nullptr, 0, k1, stats + 1920);
  k_head<<<10000, 256, 0, stream>>>(k1, stats + 1920, keep_g, keep_bb,
                                    keep_w2, keep_b2, out, 64);

  // uniq head (concat [p2 norm, a2 norm]; u1 aliases a1+N*64)
  k_gemm<<<dim3(625, 2), 256, 0, stream>>>(
      p2, stats + 384, pos_g2, pos_bb2, 256, 1,
      a2, stats + 1408, agg_g2, agg_bb2, 256,
      uniqw1T, uniq_b1, 128, nullptr, 0, u1, stats + 2048);
  k_head<<<10000, 256, 0, stream>>>(u1, stats + 2048, uniq_g, uniq_bb,
                                    uniq_w2, uniq_b2, out + NPTS, 128);

  // neighbors_index passthrough (f32 values)
  k_idx<<<1250, 256, 0, stream>>>(nbr, out + 2*NPTS);
}

// Round 6
// 460.508 us; speedup vs baseline: 1.8353x; 1.1570x over previous
//
#include <hip/hip_runtime.h>
#include <math.h>

// ---------------------------------------------------------------------------
// BimodalCompressor: KPConv point network (round 6)
// Fused sparse KPConv+conv MFMA kernel; MFMA bf16 MLP GEMMs; f32 outputs.
// Sparsity: infl[n,k,p]=max(1-d/ext,0) is ~0 for random data (ext~1.02,
// |nb|~14) -> per-pair gating + per-(p,half) K-chunk gating, all exact.
// ---------------------------------------------------------------------------

#define NPTS 40000
#define KNB  32
#define PKP  15
#define SLOPE 0.01f
#define BNEPS 1e-5f
#define INV_N (1.0f/40000.0f)

typedef __attribute__((ext_vector_type(8))) short bf16x8;
typedef __attribute__((ext_vector_type(4))) float f32x4;

__device__ __forceinline__ float lrelu(float x){ return x >= 0.0f ? x : SLOPE*x; }
__device__ __forceinline__ unsigned short f2bf(float f){
  unsigned int b = __float_as_uint(f);
  b += 0x7fffu + ((b>>16)&1u);            // round-to-nearest-even
  return (unsigned short)(b>>16);
}
__device__ __forceinline__ float bf2f(unsigned short u){
  return __uint_as_float(((unsigned int)u)<<16);
}

// --------------------------------------------------------------------------
// K0: all weight transposes in one launch. Segments laid contiguously in wT.
// --------------------------------------------------------------------------
__global__ __launch_bounds__(256) void k_wprep_all(
    const float* __restrict__ kpw,  const float* __restrict__ pw2,
    const float* __restrict__ aw1,  const float* __restrict__ aw2,
    const float* __restrict__ kw1,  const float* __restrict__ uw1,
    unsigned short* __restrict__ wT){
  int i = blockIdx.x*256 + threadIdx.x;   // 0 .. 442367 (grid exact)
  const float* src; int K, N, off, li;
  if      (i < 245760){ src=kpw; K=1920; N=128; off=0;      li=i; }
  else if (i < 262144){ src=pw2; K=64;   N=256; off=245760; li=i-245760; }
  else if (i < 294912){ src=aw1; K=128;  N=256; off=262144; li=i-262144; }
  else if (i < 360448){ src=aw2; K=256;  N=256; off=294912; li=i-294912; }
  else if (i < 376832){ src=kw1; K=256;  N=64;  off=360448; li=i-360448; }
  else                { src=uw1; K=512;  N=128; off=376832; li=i-376832; }
  int k = li / N, n = li - k*N;
  wT[(size_t)off + (size_t)n*K + k] = f2bf(src[li]);
}

// --------------------------------------------------------------------------
// K1: preact(bf16) = cov[N,9] @ pre_w[9,128] + pre_b ; stats (fp32 atomics)
// --------------------------------------------------------------------------
__global__ __launch_bounds__(256) void k_pre(
    const float* __restrict__ cov, const float* __restrict__ w,
    const float* __restrict__ b, unsigned short* __restrict__ preact,
    float* __restrict__ stats){
  __shared__ float sW[9*128];
  __shared__ float sX[32*9];
  __shared__ float sSum[2][128], sSq[2][128];
  int tid = threadIdx.x;
  int row0 = blockIdx.x*32;
  for (int i = tid; i < 9*128; i += 256) sW[i] = w[i];
  for (int i = tid; i < 32*9;  i += 256) sX[i] = cov[row0*9 + i];
  __syncthreads();
  int c = tid & 127, h = tid >> 7;
  float bias = b[c];
  float ls = 0.0f, lq = 0.0f;
  for (int r = h*16; r < h*16+16; ++r){
    float acc = bias;
    #pragma unroll
    for (int i = 0; i < 9; ++i) acc += sX[r*9+i]*sW[i*128+c];
    preact[(size_t)(row0+r)*128 + c] = f2bf(acc);
    ls += acc; lq += acc*acc;
  }
  sSum[h][c] = ls; sSq[h][c] = lq;
  __syncthreads();
  if (h == 0){
    atomicAdd(&stats[c],     sSum[0][c]+sSum[1][c]);
    atomicAdd(&stats[128+c], sSq[0][c]+sSq[1][c]);
  }
}

// --------------------------------------------------------------------------
// K2: feat(bf16) = lrelu(bn(preact)) ; fsum[n] (fp32)
// --------------------------------------------------------------------------
__global__ __launch_bounds__(256) void k_prenorm(
    const unsigned short* __restrict__ preact, const float* __restrict__ stats,
    const float* __restrict__ g, const float* __restrict__ b,
    unsigned short* __restrict__ feat, float* __restrict__ fsum){
  int wid  = (int)((blockIdx.x*256 + threadIdx.x) >> 6);
  int lane = threadIdx.x & 63;
  if (wid >= NPTS) return;
  float su = stats[lane], sq = stats[128+lane];
  float mean = su*INV_N, var = sq*INV_N - mean*mean;
  float s0 = g[lane]*rsqrtf(var+BNEPS), h0 = b[lane]-mean*s0;
  su = stats[64+lane]; sq = stats[192+lane];
  mean = su*INV_N; var = sq*INV_N - mean*mean;
  float s1 = g[64+lane]*rsqrtf(var+BNEPS), h1 = b[64+lane]-mean*s1;
  size_t off = (size_t)wid*128;
  float f0 = lrelu(bf2f(preact[off+lane])*s0+h0);
  float f1 = lrelu(bf2f(preact[off+64+lane])*s1+h1);
  feat[off+lane]    = f2bf(f0);
  feat[off+64+lane] = f2bf(f1);
  float t = f0 + f1;
  #pragma unroll
  for (int o = 32; o; o >>= 1) t += __shfl_down(t, o, 64);
  if (lane == 0) fsum[wid] = t;
}

// --------------------------------------------------------------------------
// K3 fused sparse KPConv + conv GEMM.
// Block = 64 points x 128 out-cols, 256 thr (4 waves x 16-row bands).
// kpconv_feature[n,d] = invn[n] * sum_{p,c} wtd[n,p*128+c]*kpwT[d,p*128+c]
//   wtd[n,p*128+c] = sum_k infl[n,k,p]*feat[idx[n,k],c]  (built in VGPR A-frags,
//   only for active pairs; K-chunks (p,half) skipped unless pmask bit p set)
// Deterministic: pairs iterated (r asc, k asc) via per-row bitmasks.
// --------------------------------------------------------------------------
__global__ __launch_bounds__(256) void k_kpc(
    const float* __restrict__ pts, const int* __restrict__ nbr,
    const float* __restrict__ kp, const unsigned short* __restrict__ feat,
    const float* __restrict__ fsum, const unsigned short* __restrict__ kpwT,
    unsigned short* __restrict__ kpf, float ext2, float inv_ext){
  __shared__ float sKP[16][3];
  __shared__ int   sIdx[2048];
  __shared__ float sNb[2048][3];          // 24 KB
  __shared__ unsigned int sRowMask[64];
  __shared__ float sCnt[64];
  __shared__ unsigned int sPmask;
  __shared__ unsigned short sB[8192];     // [128 d][64 k] bf16, XOR-swizzled
  int tid = threadIdx.x;
  int n0 = blockIdx.x*64;
  int w = tid >> 6, l = tid & 63;
  if (tid < 45) sKP[tid/3][tid%3] = kp[tid];
  if (tid < 64){ sRowMask[tid] = 0u; sCnt[tid] = 0.0f; }
  if (tid == 0) sPmask = 0u;
  for (int i = tid; i < 2048; i += 256) sIdx[i] = nbr[(size_t)n0*KNB + i];
  __syncthreads();
  for (int i = tid; i < 2048; i += 256){
    int r = i >> 5;
    int j = sIdx[i];
    float nx = pts[j*3+0] - pts[(n0+r)*3+0];
    float ny = pts[j*3+1] - pts[(n0+r)*3+1];
    float nz = pts[j*3+2] - pts[(n0+r)*3+2];
    sNb[i][0] = nx; sNb[i][1] = ny; sNb[i][2] = nz;
    if (fsum[j] > 0.0f) atomicAdd(&sCnt[r], 1.0f);
    unsigned int pm = 0;
    #pragma unroll
    for (int p = 0; p < PKP; ++p){
      float dx = nx - sKP[p][0], dy = ny - sKP[p][1], dz = nz - sKP[p][2];
      float d2 = dx*dx + dy*dy + dz*dz;
      if (d2 < ext2) pm |= (1u << p);
    }
    if (pm){
      atomicOr(&sRowMask[i >> 5], 1u << (i & 31));
      atomicOr(&sPmask, pm);
    }
  }
  __syncthreads();
  unsigned int pmask = sPmask;
  // wave-active: does this wave's 16-row band contain any active row?
  bool waveAct = false;
  for (int r = w*16; r < w*16+16; ++r) waveAct |= (sRowMask[r] != 0u);
  f32x4 acc[8] = {};
  for (int p = 0; p < PKP; ++p){
    if (!(pmask & (1u << p))) continue;
    float kx = sKP[p][0], ky = sKP[p][1], kz = sKP[p][2];
    for (int half = 0; half < 2; ++half){
      int kc = p*128 + half*64;
      // stage B (issue early; overlaps pair loop)
      #pragma unroll
      for (int s4 = 0; s4 < 4; ++s4){
        int cid = tid + s4*256;
        int d = cid >> 3, s = cid & 7;
        uint4 v = *(const uint4*)(kpwT + (size_t)d*1920 + kc + s*8);
        int byteB = (d*128 + s*16) ^ ((d&7)<<4);
        *(uint4*)((char*)sB + byteB) = v;
      }
      // A-fragments in VGPR (zero + sparse updates)
      float af[16];
      #pragma unroll
      for (int q = 0; q < 16; ++q) af[q] = 0.0f;
      if (waveAct){
        int g = l >> 4;
        for (int r = w*16; r < w*16+16; ++r){
          unsigned int m = sRowMask[r];
          if (!m) continue;
          bool mine = ((l & 15) == (r & 15));
          while (m){
            int k = __ffs(m) - 1;
            m &= m - 1;
            int i = (r << 5) | k;
            float dx = sNb[i][0]-kx, dy = sNb[i][1]-ky, dz = sNb[i][2]-kz;
            float d2 = dx*dx + dy*dy + dz*dz;
            float infl = 1.0f - sqrtf(d2)*inv_ext;
            if (infl <= 0.0f) continue;
            if (mine){
              const unsigned short* fp = feat + (size_t)sIdx[i]*128 + half*64;
              uint4 v0 = *(const uint4*)(fp + (g<<3));
              uint4 v1 = *(const uint4*)(fp + 32 + (g<<3));
              unsigned int e0[4] = {v0.x, v0.y, v0.z, v0.w};
              unsigned int e1[4] = {v1.x, v1.y, v1.z, v1.w};
              #pragma unroll
              for (int q = 0; q < 4; ++q){
                af[2*q+0]   += infl * bf2f((unsigned short)(e0[q] & 0xffff));
                af[2*q+1]   += infl * bf2f((unsigned short)(e0[q] >> 16));
                af[8+2*q+0] += infl * bf2f((unsigned short)(e1[q] & 0xffff));
                af[8+2*q+1] += infl * bf2f((unsigned short)(e1[q] >> 16));
              }
            }
          }
        }
      }
      __syncthreads();               // B staged; af done
      if (waveAct){
        bf16x8 a0, a1;
        #pragma unroll
        for (int q = 0; q < 8; ++q){
          ((unsigned short*)&a0)[q] = f2bf(af[q]);
          ((unsigned short*)&a1)[q] = f2bf(af[8+q]);
        }
        int k0 = (l >> 4)*8;
        #pragma unroll
        for (int cf = 0; cf < 8; ++cf){
          int colB = cf*16 + (l & 15);
          int byte0 = (colB*128 + k0*2)      ^ ((colB&7)<<4);
          int byte1 = (colB*128 + (32+k0)*2) ^ ((colB&7)<<4);
          bf16x8 b0 = *(const bf16x8*)((const char*)sB + byte0);
          bf16x8 b1 = *(const bf16x8*)((const char*)sB + byte1);
          acc[cf] = __builtin_amdgcn_mfma_f32_16x16x32_bf16(a0, b0, acc[cf], 0,0,0);
          acc[cf] = __builtin_amdgcn_mfma_f32_16x16x32_bf16(a1, b1, acc[cf], 0,0,0);
        }
      }
      __syncthreads();               // done reading sB
    }
  }
  if (tid < 64) sCnt[tid] = 1.0f / fmaxf(sCnt[tid], 1.0f);
  __syncthreads();
  #pragma unroll
  for (int cf = 0; cf < 8; ++cf){
    int col = cf*16 + (l & 15);
    #pragma unroll
    for (int r = 0; r < 4; ++r){
      int row = w*16 + (l >> 4)*4 + r;
      kpf[(size_t)(n0+row)*128 + col] = f2bf(acc[cf][r] * sCnt[row]);
    }
  }
}

// --------------------------------------------------------------------------
// K4 MFMA GEMM (as round 5): Y(bf16) = epi( norm(X0|X1) @ Wt + bias )
// --------------------------------------------------------------------------
__global__ __launch_bounds__(256) void k_gemm(
    const unsigned short* __restrict__ X0, const float* __restrict__ st0,
    const float* __restrict__ g0, const float* __restrict__ b0,
    int K0, int norm0,
    const unsigned short* __restrict__ X1, const float* __restrict__ st1,
    const float* __restrict__ g1, const float* __restrict__ b1, int K1,
    const unsigned short* __restrict__ Wt, const float* __restrict__ bias,
    int NOUT, unsigned short* __restrict__ Y, float* __restrict__ statsOut){
  __shared__ unsigned short sA[64*64];
  __shared__ unsigned short sB[64*64];
  __shared__ float sSc[64], sSh[64];
  __shared__ float sSum[64], sSq[64];
  int tid = threadIdx.x;
  int row0 = blockIdx.x*64;
  int ct   = blockIdx.y*64;
  int w = tid >> 6, l = tid & 63;
  int KT = K0 + K1;
  if (tid < 64){ sSum[tid] = 0.0f; sSq[tid] = 0.0f; }
  f32x4 acc[4] = {};
  for (int kc = 0; kc < KT; kc += 64){
    bool sel1 = (kc >= K0);
    const unsigned short* Xp = sel1 ? X1 : X0;
    int Ks = sel1 ? K1 : K0;
    int cb = sel1 ? kc - K0 : kc;
    int nf = sel1 ? 1 : norm0;
    if (tid < 64){
      if (nf){
        const float* st = sel1 ? st1 : st0;
        const float* gg = sel1 ? g1 : g0;
        const float* bb = sel1 ? b1 : b0;
        int ch = cb + tid;
        float s = st[ch], q = st[Ks+ch];
        float mean = s*INV_N, var = q*INV_N - mean*mean;
        float sc = gg[ch]*rsqrtf(var+BNEPS);
        sSc[tid] = sc; sSh[tid] = bb[ch] - mean*sc;
      }
    }
    __syncthreads();
    #pragma unroll
    for (int p = 0; p < 2; ++p){
      int r = (tid >> 3) + p*32;
      int k0 = (tid & 7)*8;
      uint4 v = *(const uint4*)(Xp + (size_t)(row0+r)*Ks + cb + k0);
      if (nf){
        unsigned short e[8] = {(unsigned short)(v.x&0xffff),(unsigned short)(v.x>>16),
                               (unsigned short)(v.y&0xffff),(unsigned short)(v.y>>16),
                               (unsigned short)(v.z&0xffff),(unsigned short)(v.z>>16),
                               (unsigned short)(v.w&0xffff),(unsigned short)(v.w>>16)};
        unsigned short o[8];
        #pragma unroll
        for (int j = 0; j < 8; ++j){
          float f = lrelu(bf2f(e[j])*sSc[k0+j] + sSh[k0+j]);
          o[j] = f2bf(f);
        }
        v.x = (uint)o[0] | ((uint)o[1]<<16);
        v.y = (uint)o[2] | ((uint)o[3]<<16);
        v.z = (uint)o[4] | ((uint)o[5]<<16);
        v.w = (uint)o[6] | ((uint)o[7]<<16);
      }
      int byteA = (r*128 + k0*2) ^ ((r&7)<<4);
      *(uint4*)((char*)sA + byteA) = v;
      uint4 vb = *(const uint4*)(Wt + (size_t)(ct+r)*KT + kc + k0);
      int byteB = (r*128 + k0*2) ^ ((r&7)<<4);
      *(uint4*)((char*)sB + byteB) = vb;
    }
    __syncthreads();
    int rowA = w*16 + (l & 15);
    #pragma unroll
    for (int m = 0; m < 2; ++m){
      int ka = m*32 + (l >> 4)*8;
      int byteA = (rowA*128 + ka*2) ^ ((rowA&7)<<4);
      bf16x8 af = *(const bf16x8*)((const char*)sA + byteA);
      #pragma unroll
      for (int cf = 0; cf < 4; ++cf){
        int colB = cf*16 + (l & 15);
        int byteB = (colB*128 + ka*2) ^ ((colB&7)<<4);
        bf16x8 bfr = *(const bf16x8*)((const char*)sB + byteB);
        acc[cf] = __builtin_amdgcn_mfma_f32_16x16x32_bf16(af, bfr, acc[cf], 0, 0, 0);
      }
    }
    __syncthreads();
  }
  float cs[4] = {0,0,0,0}, cq[4] = {0,0,0,0};
  #pragma unroll
  for (int cf = 0; cf < 4; ++cf){
    int col = ct + cf*16 + (l & 15);
    float bj = bias ? bias[col] : 0.0f;
    #pragma unroll
    for (int r = 0; r < 4; ++r){
      int grow = row0 + w*16 + (l >> 4)*4 + r;
      float v = acc[cf][r] + bj;
      Y[(size_t)grow*NOUT + col] = f2bf(v);
      cs[cf] += v; cq[cf] += v*v;
    }
  }
  if (statsOut){
    #pragma unroll
    for (int cf = 0; cf < 4; ++cf){
      atomicAdd(&sSum[cf*16 + (l&15)], cs[cf]);
      atomicAdd(&sSq[cf*16 + (l&15)],  cq[cf]);
    }
    __syncthreads();
    if (tid < 64){
      atomicAdd(&statsOut[ct+tid],      sSum[tid]);
      atomicAdd(&statsOut[NOUT+ct+tid], sSq[tid]);
    }
  }
}

// --------------------------------------------------------------------------
// K5: p1(bf16) = points[N,3] @ pos_w1[3,64] + b ; stats
// --------------------------------------------------------------------------
__global__ __launch_bounds__(256) void k_pos1(
    const float* __restrict__ pts, const float* __restrict__ w,
    const float* __restrict__ b, unsigned short* __restrict__ p1,
    float* __restrict__ stats){
  __shared__ float sSum[4][64], sSq[4][64];
  int tid = threadIdx.x;
  int c = tid & 63, grp = tid >> 6;
  int row0 = blockIdx.x*32;
  float w0 = w[c], w1 = w[64+c], w2 = w[128+c], bb = b[c];
  float ls = 0.0f, lq = 0.0f;
  for (int r = row0 + grp*8; r < row0 + grp*8 + 8; ++r){
    float x0 = pts[r*3+0], x1 = pts[r*3+1], x2 = pts[r*3+2];
    float y = bb + x0*w0 + x1*w1 + x2*w2;
    p1[(size_t)r*64 + c] = f2bf(y);
    ls += y; lq += y*y;
  }
  sSum[grp][c] = ls; sSq[grp][c] = lq;
  __syncthreads();
  if (grp == 0){
    atomicAdd(&stats[c],    sSum[0][c]+sSum[1][c]+sSum[2][c]+sSum[3][c]);
    atomicAdd(&stats[64+c], sSq[0][c]+sSq[1][c]+sSq[2][c]+sSq[3][c]);
  }
}

// --------------------------------------------------------------------------
// K7 head: out[n] = f32(sigmoid( sum_c lrelu(bn(H[n,c]))*w2[c] + b2 ))
// --------------------------------------------------------------------------
__global__ __launch_bounds__(256) void k_head(
    const unsigned short* __restrict__ H, const float* __restrict__ stats,
    const float* __restrict__ g, const float* __restrict__ b,
    const float* __restrict__ w2, const float* __restrict__ b2,
    float* __restrict__ out, int Cdim){
  int wid  = (int)((blockIdx.x*256 + threadIdx.x) >> 6);
  int lane = threadIdx.x & 63;
  if (wid >= NPTS) return;
  float acc = 0.0f;
  for (int c = lane; c < Cdim; c += 64){
    float su = stats[c], sq = stats[Cdim+c];
    float mean = su*INV_N, var = sq*INV_N - mean*mean;
    float sc = g[c]*rsqrtf(var+BNEPS), sh = b[c]-mean*sc;
    float h = lrelu(bf2f(H[(size_t)wid*Cdim + c])*sc + sh);
    acc += h * w2[c];
  }
  #pragma unroll
  for (int o = 32; o; o >>= 1) acc += __shfl_down(acc, o, 64);
  if (lane == 0){
    float x = acc + b2[0];
    out[wid] = 1.0f/(1.0f + expf(-x));
  }
}

// --------------------------------------------------------------------------
// K8: neighbors_index passthrough as float32
// --------------------------------------------------------------------------
__global__ __launch_bounds__(256) void k_idx(
    const int* __restrict__ nbr, float* __restrict__ o){
  int i = blockIdx.x*256 + threadIdx.x;           // grid sized exactly
  int4 v = ((const int4*)nbr)[i];
  ((float4*)o)[i] = make_float4((float)v.x,(float)v.y,(float)v.z,(float)v.w);
}

// --------------------------------------------------------------------------
extern "C" void kernel_launch(void* const* d_in, const int* in_sizes, int n_in,
                              void* d_out, int out_size, void* d_ws, size_t ws_size,
                              hipStream_t stream) {
  const float* pts    = (const float*)d_in[0];
  const float* cov    = (const float*)d_in[1];
  const int*   nbr    = (const int*)  d_in[2];
  const float* pre_w  = (const float*)d_in[3];
  const float* pre_b  = (const float*)d_in[4];
  const float* pre_g  = (const float*)d_in[5];
  const float* pre_bb = (const float*)d_in[6];
  const float* kp     = (const float*)d_in[7];
  const float* kpw    = (const float*)d_in[8];
  const float* pos_w1 = (const float*)d_in[9];
  const float* pos_b1 = (const float*)d_in[10];
  const float* pos_g1 = (const float*)d_in[11];
  const float* pos_bb1= (const float*)d_in[12];
  const float* pos_w2 = (const float*)d_in[13];
  const float* pos_b2 = (const float*)d_in[14];
  const float* pos_g2 = (const float*)d_in[15];
  const float* pos_bb2= (const float*)d_in[16];
  const float* agg_w1 = (const float*)d_in[17];
  const float* agg_b1 = (const float*)d_in[18];
  const float* agg_g1 = (const float*)d_in[19];
  const float* agg_bb1= (const float*)d_in[20];
  const float* agg_w2 = (const float*)d_in[21];
  const float* agg_b2 = (const float*)d_in[22];
  const float* agg_g2 = (const float*)d_in[23];
  const float* agg_bb2= (const float*)d_in[24];
  const float* keep_w1= (const float*)d_in[25];
  const float* keep_b1= (const float*)d_in[26];
  const float* keep_g = (const float*)d_in[27];
  const float* keep_bb= (const float*)d_in[28];
  const float* keep_w2= (const float*)d_in[29];
  const float* keep_b2= (const float*)d_in[30];
  const float* uniq_w1= (const float*)d_in[31];
  const float* uniq_b1= (const float*)d_in[32];
  const float* uniq_g = (const float*)d_in[33];
  const float* uniq_bb= (const float*)d_in[34];
  const float* uniq_w2= (const float*)d_in[35];
  const float* uniq_b2= (const float*)d_in[36];

  float* out = (float*)d_out;     // f32 [match(N) | unique(N) | idx(N*K)]

  // ---- ws layout ----
  char* wsb = (char*)d_ws;
  size_t off = 0;
  float* stats = (float*)(wsb + off); off += 4096*4;
  unsigned short* wT = (unsigned short*)(wsb + off); off += (size_t)442368*2;
  unsigned short* kpwT   = wT;
  unsigned short* posw2T = wT + 245760;
  unsigned short* aggw1T = wT + 262144;
  unsigned short* aggw2T = wT + 294912;
  unsigned short* keepw1T= wT + 360448;
  unsigned short* uniqw1T= wT + 376832;
  float* fsum  = (float*)(wsb + off); off += (size_t)NPTS*4;
  unsigned short* kpf  = (unsigned short*)(wsb + off); off += (size_t)NPTS*128*2;
  unsigned short* feat = (unsigned short*)(wsb + off); off += (size_t)NPTS*128*2;
  unsigned short* p2   = (unsigned short*)(wsb + off); off += (size_t)NPTS*256*2;
  unsigned short* a2   = (unsigned short*)(wsb + off); off += (size_t)NPTS*256*2;
  unsigned short* a1   = (unsigned short*)(wsb + off); off += (size_t)NPTS*256*2;
  unsigned short* preact = p2;            // dead before p2 written
  unsigned short* p1 = feat;              // feat dead after k_kpc
  unsigned short* k1 = a1;                // a1 dead after agg2
  unsigned short* u1 = a1 + (size_t)NPTS*64;

  const double kpe = 1.0 / (cbrt(15.0) - 1.0) * 1.5;   // KP_EXTENT
  const float inv_ext = (float)(1.0 / kpe);
  const float ext2 = (float)(kpe * kpe);

  hipMemsetAsync(stats, 0, 2304*sizeof(float), stream);

  k_wprep_all<<<1728, 256, 0, stream>>>(kpw, pos_w2, agg_w1, agg_w2,
                                        keep_w1, uniq_w1, wT);

  // pre layer
  k_pre<<<1250, 256, 0, stream>>>(cov, pre_w, pre_b, preact, stats + 0);
  k_prenorm<<<10000, 256, 0, stream>>>(preact, stats + 0, pre_g, pre_bb, feat, fsum);

  // fused sparse KPConv + conv
  k_kpc<<<625, 256, 0, stream>>>(pts, nbr, kp, feat, fsum, kpwT, kpf,
                                 ext2, inv_ext);

  // pos branch (p1 aliases feat)
  k_pos1<<<1250, 256, 0, stream>>>(pts, pos_w1, pos_b1, p1, stats + 256);
  k_gemm<<<dim3(625, 4), 256, 0, stream>>>(
      p1, stats + 256, pos_g1, pos_bb1, 64, 1,
      nullptr, nullptr, nullptr, nullptr, 0,
      posw2T, pos_b2, 256, p2, stats + 384);

  // agg branch
  k_gemm<<<dim3(625, 4), 256, 0, stream>>>(
      kpf, nullptr, nullptr, nullptr, 128, 0,
      nullptr, nullptr, nullptr, nullptr, 0,
      aggw1T, agg_b1, 256, a1, stats + 896);
  k_gemm<<<dim3(625, 4), 256, 0, stream>>>(
      a1, stats + 896, agg_g1, agg_bb1, 256, 1,
      nullptr, nullptr, nullptr, nullptr, 0,
      aggw2T, agg_b2, 256, a2, stats + 1408);

  // keep head
  k_gemm<<<dim3(625, 1), 256, 0, stream>>>(
      a2, stats + 1408, agg_g2, agg_bb2, 256, 1,
      nullptr, nullptr, nullptr, nullptr, 0,
      keepw1T, keep_b1, 64, k1, stats + 1920);
  k_head<<<10000, 256, 0, stream>>>(k1, stats + 1920, keep_g, keep_bb,
                                    keep_w2, keep_b2, out, 64);

  // uniq head
  k_gemm<<<dim3(625, 2), 256, 0, stream>>>(
      p2, stats + 384, pos_g2, pos_bb2, 256, 1,
      a2, stats + 1408, agg_g2, agg_bb2, 256,
      uniqw1T, uniq_b1, 128, u1, stats + 2048);
  k_head<<<10000, 256, 0, stream>>>(u1, stats + 2048, uniq_g, uniq_bb,
                                    uniq_w2, uniq_b2, out + NPTS, 128);

  // neighbors_index passthrough
  k_idx<<<1250, 256, 0, stream>>>(nbr, out + 2*NPTS);
}

// Round 7
// 410.274 us; speedup vs baseline: 2.0601x; 1.1224x over previous
//
#include <hip/hip_runtime.h>
#include <math.h>

// ---------------------------------------------------------------------------
// BimodalCompressor: KPConv point network (round 7)
// Sparse KPConv via row compaction: ~2% of rows have any neighbor within
// KP_EXTENT (P_pair ~ 7e-4, P_row = 1-(1-P)^32 ~ 2%); 98% of kpf rows are
// exactly 0. k_scan finds active rows; k_conv_act computes only those.
// MFMA bf16 MLP GEMMs; f32 outputs.
// ---------------------------------------------------------------------------

#define NPTS 40000
#define KNB  32
#define PKP  15
#define SLOPE 0.01f
#define BNEPS 1e-5f
#define INV_N (1.0f/40000.0f)

typedef __attribute__((ext_vector_type(8))) short bf16x8;
typedef __attribute__((ext_vector_type(4))) float f32x4;

__device__ __forceinline__ float lrelu(float x){ return x >= 0.0f ? x : SLOPE*x; }
__device__ __forceinline__ unsigned short f2bf(float f){
  unsigned int b = __float_as_uint(f);
  b += 0x7fffu + ((b>>16)&1u);            // round-to-nearest-even
  return (unsigned short)(b>>16);
}
__device__ __forceinline__ float bf2f(unsigned short u){
  return __uint_as_float(((unsigned int)u)<<16);
}

// --------------------------------------------------------------------------
// K0: all weight transposes in one launch. Segments laid contiguously in wT.
// --------------------------------------------------------------------------
__global__ __launch_bounds__(256) void k_wprep_all(
    const float* __restrict__ kpw,  const float* __restrict__ pw2,
    const float* __restrict__ aw1,  const float* __restrict__ aw2,
    const float* __restrict__ kw1,  const float* __restrict__ uw1,
    unsigned short* __restrict__ wT){
  int i = blockIdx.x*256 + threadIdx.x;   // 0 .. 442367 (grid exact)
  const float* src; int K, N, off, li;
  if      (i < 245760){ src=kpw; K=1920; N=128; off=0;      li=i; }
  else if (i < 262144){ src=pw2; K=64;   N=256; off=245760; li=i-245760; }
  else if (i < 294912){ src=aw1; K=128;  N=256; off=262144; li=i-262144; }
  else if (i < 360448){ src=aw2; K=256;  N=256; off=294912; li=i-294912; }
  else if (i < 376832){ src=kw1; K=256;  N=64;  off=360448; li=i-360448; }
  else                { src=uw1; K=512;  N=128; off=376832; li=i-376832; }
  int k = li / N, n = li - k*N;
  wT[(size_t)off + (size_t)n*K + k] = f2bf(src[li]);
}

// --------------------------------------------------------------------------
// K1: preact(bf16) = cov[N,9] @ pre_w[9,128] + pre_b ; stats (fp32 atomics)
// --------------------------------------------------------------------------
__global__ __launch_bounds__(256) void k_pre(
    const float* __restrict__ cov, const float* __restrict__ w,
    const float* __restrict__ b, unsigned short* __restrict__ preact,
    float* __restrict__ stats){
  __shared__ float sW[9*128];
  __shared__ float sX[32*9];
  __shared__ float sSum[2][128], sSq[2][128];
  int tid = threadIdx.x;
  int row0 = blockIdx.x*32;
  for (int i = tid; i < 9*128; i += 256) sW[i] = w[i];
  for (int i = tid; i < 32*9;  i += 256) sX[i] = cov[row0*9 + i];
  __syncthreads();
  int c = tid & 127, h = tid >> 7;
  float bias = b[c];
  float ls = 0.0f, lq = 0.0f;
  for (int r = h*16; r < h*16+16; ++r){
    float acc = bias;
    #pragma unroll
    for (int i = 0; i < 9; ++i) acc += sX[r*9+i]*sW[i*128+c];
    preact[(size_t)(row0+r)*128 + c] = f2bf(acc);
    ls += acc; lq += acc*acc;
  }
  sSum[h][c] = ls; sSq[h][c] = lq;
  __syncthreads();
  if (h == 0){
    atomicAdd(&stats[c],     sSum[0][c]+sSum[1][c]);
    atomicAdd(&stats[128+c], sSq[0][c]+sSq[1][c]);
  }
}

// --------------------------------------------------------------------------
// K2: feat(bf16) = lrelu(bn(preact)) ; fsum[n] (fp32)
// --------------------------------------------------------------------------
__global__ __launch_bounds__(256) void k_prenorm(
    const unsigned short* __restrict__ preact, const float* __restrict__ stats,
    const float* __restrict__ g, const float* __restrict__ b,
    unsigned short* __restrict__ feat, float* __restrict__ fsum){
  int wid  = (int)((blockIdx.x*256 + threadIdx.x) >> 6);
  int lane = threadIdx.x & 63;
  if (wid >= NPTS) return;
  float su = stats[lane], sq = stats[128+lane];
  float mean = su*INV_N, var = sq*INV_N - mean*mean;
  float s0 = g[lane]*rsqrtf(var+BNEPS), h0 = b[lane]-mean*s0;
  su = stats[64+lane]; sq = stats[192+lane];
  mean = su*INV_N; var = sq*INV_N - mean*mean;
  float s1 = g[64+lane]*rsqrtf(var+BNEPS), h1 = b[64+lane]-mean*s1;
  size_t off = (size_t)wid*128;
  float f0 = lrelu(bf2f(preact[off+lane])*s0+h0);
  float f1 = lrelu(bf2f(preact[off+64+lane])*s1+h1);
  feat[off+lane]    = f2bf(f0);
  feat[off+64+lane] = f2bf(f1);
  float t = f0 + f1;
  #pragma unroll
  for (int o = 32; o; o >>= 1) t += __shfl_down(t, o, 64);
  if (lane == 0) fsum[wid] = t;
}

// --------------------------------------------------------------------------
// K3a scan: one half-wave (32 lanes) per row. Computes invn[n], zeroes
// kpf[n,:], appends rows with any active (k,p) pair to list (order of list
// is non-deterministic; per-row outputs are order-independent).
// Grid 5000 x 256: wave wv handles rows 2*wv, 2*wv+1.
// --------------------------------------------------------------------------
__global__ __launch_bounds__(256) void k_scan(
    const float* __restrict__ pts, const int* __restrict__ nbr,
    const float* __restrict__ kp, const float* __restrict__ fsum,
    unsigned short* __restrict__ kpf, float* __restrict__ invn,
    int* __restrict__ list, int* __restrict__ gcount, float ext2){
  __shared__ float sKP[45];
  if (threadIdx.x < 45) sKP[threadIdx.x] = kp[threadIdx.x];
  __syncthreads();
  int wv   = (blockIdx.x*256 + threadIdx.x) >> 6;
  int lane = threadIdx.x & 63;
  int half = lane >> 5;
  int kk   = lane & 31;
  int n    = wv*2 + half;
  float px = pts[n*3+0], py = pts[n*3+1], pz = pts[n*3+2];
  int j = nbr[(size_t)n*KNB + kk];
  float nx = pts[j*3+0] - px;
  float ny = pts[j*3+1] - py;
  float nz = pts[j*3+2] - pz;
  float fs = fsum[j];
  bool anyp = false;
  #pragma unroll
  for (int p = 0; p < PKP; ++p){
    float dx = nx - sKP[p*3+0], dy = ny - sKP[p*3+1], dz = nz - sKP[p*3+2];
    anyp |= (dx*dx + dy*dy + dz*dz < ext2);
  }
  unsigned long long act  = __ballot(anyp);
  unsigned long long good = __ballot(fs > 0.0f);
  unsigned int actH  = half ? (unsigned int)(act  >> 32) : (unsigned int)act;
  unsigned int goodH = half ? (unsigned int)(good >> 32) : (unsigned int)good;
  // zero kpf row: 32 lanes x 8B = 256B
  uint2 z; z.x = 0u; z.y = 0u;
  *(uint2*)(kpf + (size_t)n*128 + kk*4) = z;
  if (kk == 0){
    int cnt = __popc(goodH);
    invn[n] = 1.0f / (float)(cnt < 1 ? 1 : cnt);
    if (actH){
      int pos = atomicAdd(gcount, 1);
      list[pos] = n;
    }
  }
}

// --------------------------------------------------------------------------
// K3b: dense conv for active rows only (~2% of N). Grid-stride over list.
// Per row: infl[32][15] -> weighted[15][128] in LDS (single-owner determin-
// istic accumulation) -> matvec over active p-slices of kpwT -> kpf row.
// --------------------------------------------------------------------------
__global__ __launch_bounds__(256) void k_conv_act(
    const float* __restrict__ pts, const int* __restrict__ nbr,
    const float* __restrict__ kp, const unsigned short* __restrict__ feat,
    const unsigned short* __restrict__ kpwT, const float* __restrict__ invn,
    const int* __restrict__ list, const int* __restrict__ gcount,
    unsigned short* __restrict__ kpf, float ext2, float inv_ext){
  __shared__ float sW[PKP*128];        // weighted, f32
  __shared__ float sInfl[KNB*16];
  __shared__ unsigned int sPairP[KNB];
  __shared__ float sKP[45];
  __shared__ float sOut[128];
  __shared__ unsigned int sPmask, sPact;
  int tid = threadIdx.x;
  if (tid < 45) sKP[tid] = kp[tid];
  int cnt = *gcount;
  for (int it = blockIdx.x; it < cnt; it += gridDim.x){
    int n = list[it];
    if (tid == 0){ sPmask = 0u; sPact = 0u; }
    for (int i = tid; i < PKP*128; i += 256) sW[i] = 0.0f;
    __syncthreads();
    if (tid < KNB){
      int j = nbr[(size_t)n*KNB + tid];
      sPairP[tid] = (unsigned int)j;     // stash idx temporarily? no: need both
    }
    __syncthreads();
    if (tid < KNB){
      int j = (int)sPairP[tid];
      float nx = pts[j*3+0] - pts[n*3+0];
      float ny = pts[j*3+1] - pts[n*3+1];
      float nz = pts[j*3+2] - pts[n*3+2];
      unsigned int pm = 0u;
      #pragma unroll
      for (int p = 0; p < PKP; ++p){
        float dx = nx - sKP[p*3+0], dy = ny - sKP[p*3+1], dz = nz - sKP[p*3+2];
        float d2 = dx*dx + dy*dy + dz*dz;
        float infl = 0.0f;
        if (d2 < ext2){ infl = 1.0f - sqrtf(d2)*inv_ext; pm |= (1u << p); }
        sInfl[tid*16 + p] = infl;
      }
      // re-purpose sPairP: keep j in high bits unused; store mask now,
      // but we still need j for feat loads -> recompute from nbr later.
      sPairP[tid] = pm;
      if (pm){
        atomicOr(&sPact, 1u << tid);
        atomicOr(&sPmask, pm);
      }
    }
    __syncthreads();
    // weighted accumulation: threads 0..127 own column c (single owner)
    if (tid < 128){
      int c = tid;
      unsigned int m = sPact;
      while (m){
        int k = __ffs(m) - 1; m &= m - 1;
        int j = nbr[(size_t)n*KNB + k];
        float f = bf2f(feat[(size_t)j*128 + c]);
        unsigned int pp = sPairP[k];
        while (pp){
          int p = __ffs(pp) - 1; pp &= pp - 1;
          sW[p*128 + c] += sInfl[k*16 + p] * f;
        }
      }
    }
    __syncthreads();
    // matvec: d = tid&127, h = tid>>7 splits the c-range
    int d = tid & 127, h = tid >> 7;
    float acc = 0.0f;
    unsigned int pm = sPmask;
    while (pm){
      int p = __ffs(pm) - 1; pm &= pm - 1;
      const unsigned short* wp = kpwT + (size_t)d*1920 + p*128 + h*64;
      const float* wsrc = &sW[p*128 + h*64];
      #pragma unroll
      for (int c8 = 0; c8 < 8; ++c8){
        uint4 v = *(const uint4*)(wp + c8*8);
        unsigned int e[4] = {v.x, v.y, v.z, v.w};
        #pragma unroll
        for (int q = 0; q < 4; ++q){
          acc += wsrc[c8*8 + 2*q]     * bf2f((unsigned short)(e[q] & 0xffff));
          acc += wsrc[c8*8 + 2*q + 1] * bf2f((unsigned short)(e[q] >> 16));
        }
      }
    }
    if (h == 0) sOut[d] = acc;
    __syncthreads();
    if (h == 1) kpf[(size_t)n*128 + d] = f2bf((sOut[d] + acc) * invn[n]);
    __syncthreads();
  }
}

// --------------------------------------------------------------------------
// K4 MFMA GEMM: Y(bf16) = epi( norm(X0|X1) @ Wt + bias )
// --------------------------------------------------------------------------
__global__ __launch_bounds__(256) void k_gemm(
    const unsigned short* __restrict__ X0, const float* __restrict__ st0,
    const float* __restrict__ g0, const float* __restrict__ b0,
    int K0, int norm0,
    const unsigned short* __restrict__ X1, const float* __restrict__ st1,
    const float* __restrict__ g1, const float* __restrict__ b1, int K1,
    const unsigned short* __restrict__ Wt, const float* __restrict__ bias,
    int NOUT, unsigned short* __restrict__ Y, float* __restrict__ statsOut){
  __shared__ unsigned short sA[64*64];
  __shared__ unsigned short sB[64*64];
  __shared__ float sSc[64], sSh[64];
  __shared__ float sSum[64], sSq[64];
  int tid = threadIdx.x;
  int row0 = blockIdx.x*64;
  int ct   = blockIdx.y*64;
  int w = tid >> 6, l = tid & 63;
  int KT = K0 + K1;
  if (tid < 64){ sSum[tid] = 0.0f; sSq[tid] = 0.0f; }
  f32x4 acc[4] = {};
  for (int kc = 0; kc < KT; kc += 64){
    bool sel1 = (kc >= K0);
    const unsigned short* Xp = sel1 ? X1 : X0;
    int Ks = sel1 ? K1 : K0;
    int cb = sel1 ? kc - K0 : kc;
    int nf = sel1 ? 1 : norm0;
    if (tid < 64){
      if (nf){
        const float* st = sel1 ? st1 : st0;
        const float* gg = sel1 ? g1 : g0;
        const float* bb = sel1 ? b1 : b0;
        int ch = cb + tid;
        float s = st[ch], q = st[Ks+ch];
        float mean = s*INV_N, var = q*INV_N - mean*mean;
        float sc = gg[ch]*rsqrtf(var+BNEPS);
        sSc[tid] = sc; sSh[tid] = bb[ch] - mean*sc;
      }
    }
    __syncthreads();
    #pragma unroll
    for (int p = 0; p < 2; ++p){
      int r = (tid >> 3) + p*32;
      int k0 = (tid & 7)*8;
      uint4 v = *(const uint4*)(Xp + (size_t)(row0+r)*Ks + cb + k0);
      if (nf){
        unsigned short e[8] = {(unsigned short)(v.x&0xffff),(unsigned short)(v.x>>16),
                               (unsigned short)(v.y&0xffff),(unsigned short)(v.y>>16),
                               (unsigned short)(v.z&0xffff),(unsigned short)(v.z>>16),
                               (unsigned short)(v.w&0xffff),(unsigned short)(v.w>>16)};
        unsigned short o[8];
        #pragma unroll
        for (int j = 0; j < 8; ++j){
          float f = lrelu(bf2f(e[j])*sSc[k0+j] + sSh[k0+j]);
          o[j] = f2bf(f);
        }
        v.x = (uint)o[0] | ((uint)o[1]<<16);
        v.y = (uint)o[2] | ((uint)o[3]<<16);
        v.z = (uint)o[4] | ((uint)o[5]<<16);
        v.w = (uint)o[6] | ((uint)o[7]<<16);
      }
      int byteA = (r*128 + k0*2) ^ ((r&7)<<4);
      *(uint4*)((char*)sA + byteA) = v;
      uint4 vb = *(const uint4*)(Wt + (size_t)(ct+r)*KT + kc + k0);
      int byteB = (r*128 + k0*2) ^ ((r&7)<<4);
      *(uint4*)((char*)sB + byteB) = vb;
    }
    __syncthreads();
    int rowA = w*16 + (l & 15);
    #pragma unroll
    for (int m = 0; m < 2; ++m){
      int ka = m*32 + (l >> 4)*8;
      int byteA = (rowA*128 + ka*2) ^ ((rowA&7)<<4);
      bf16x8 af = *(const bf16x8*)((const char*)sA + byteA);
      #pragma unroll
      for (int cf = 0; cf < 4; ++cf){
        int colB = cf*16 + (l & 15);
        int byteB = (colB*128 + ka*2) ^ ((colB&7)<<4);
        bf16x8 bfr = *(const bf16x8*)((const char*)sB + byteB);
        acc[cf] = __builtin_amdgcn_mfma_f32_16x16x32_bf16(af, bfr, acc[cf], 0, 0, 0);
      }
    }
    __syncthreads();
  }
  float cs[4] = {0,0,0,0}, cq[4] = {0,0,0,0};
  #pragma unroll
  for (int cf = 0; cf < 4; ++cf){
    int col = ct + cf*16 + (l & 15);
    float bj = bias ? bias[col] : 0.0f;
    #pragma unroll
    for (int r = 0; r < 4; ++r){
      int grow = row0 + w*16 + (l >> 4)*4 + r;
      float v = acc[cf][r] + bj;
      Y[(size_t)grow*NOUT + col] = f2bf(v);
      cs[cf] += v; cq[cf] += v*v;
    }
  }
  if (statsOut){
    #pragma unroll
    for (int cf = 0; cf < 4; ++cf){
      atomicAdd(&sSum[cf*16 + (l&15)], cs[cf]);
      atomicAdd(&sSq[cf*16 + (l&15)],  cq[cf]);
    }
    __syncthreads();
    if (tid < 64){
      atomicAdd(&statsOut[ct+tid],      sSum[tid]);
      atomicAdd(&statsOut[NOUT+ct+tid], sSq[tid]);
    }
  }
}

// --------------------------------------------------------------------------
// K5: p1(bf16) = points[N,3] @ pos_w1[3,64] + b ; stats
// --------------------------------------------------------------------------
__global__ __launch_bounds__(256) void k_pos1(
    const float* __restrict__ pts, const float* __restrict__ w,
    const float* __restrict__ b, unsigned short* __restrict__ p1,
    float* __restrict__ stats){
  __shared__ float sSum[4][64], sSq[4][64];
  int tid = threadIdx.x;
  int c = tid & 63, grp = tid >> 6;
  int row0 = blockIdx.x*32;
  float w0 = w[c], w1 = w[64+c], w2 = w[128+c], bb = b[c];
  float ls = 0.0f, lq = 0.0f;
  for (int r = row0 + grp*8; r < row0 + grp*8 + 8; ++r){
    float x0 = pts[r*3+0], x1 = pts[r*3+1], x2 = pts[r*3+2];
    float y = bb + x0*w0 + x1*w1 + x2*w2;
    p1[(size_t)r*64 + c] = f2bf(y);
    ls += y; lq += y*y;
  }
  sSum[grp][c] = ls; sSq[grp][c] = lq;
  __syncthreads();
  if (grp == 0){
    atomicAdd(&stats[c],    sSum[0][c]+sSum[1][c]+sSum[2][c]+sSum[3][c]);
    atomicAdd(&stats[64+c], sSq[0][c]+sSq[1][c]+sSq[2][c]+sSq[3][c]);
  }
}

// --------------------------------------------------------------------------
// K7 head: out[n] = f32(sigmoid( sum_c lrelu(bn(H[n,c]))*w2[c] + b2 ))
// --------------------------------------------------------------------------
__global__ __launch_bounds__(256) void k_head(
    const unsigned short* __restrict__ H, const float* __restrict__ stats,
    const float* __restrict__ g, const float* __restrict__ b,
    const float* __restrict__ w2, const float* __restrict__ b2,
    float* __restrict__ out, int Cdim){
  int wid  = (int)((blockIdx.x*256 + threadIdx.x) >> 6);
  int lane = threadIdx.x & 63;
  if (wid >= NPTS) return;
  float acc = 0.0f;
  for (int c = lane; c < Cdim; c += 64){
    float su = stats[c], sq = stats[Cdim+c];
    float mean = su*INV_N, var = sq*INV_N - mean*mean;
    float sc = g[c]*rsqrtf(var+BNEPS), sh = b[c]-mean*sc;
    float h = lrelu(bf2f(H[(size_t)wid*Cdim + c])*sc + sh);
    acc += h * w2[c];
  }
  #pragma unroll
  for (int o = 32; o; o >>= 1) acc += __shfl_down(acc, o, 64);
  if (lane == 0){
    float x = acc + b2[0];
    out[wid] = 1.0f/(1.0f + expf(-x));
  }
}

// --------------------------------------------------------------------------
// K8: neighbors_index passthrough as float32
// --------------------------------------------------------------------------
__global__ __launch_bounds__(256) void k_idx(
    const int* __restrict__ nbr, float* __restrict__ o){
  int i = blockIdx.x*256 + threadIdx.x;           // grid sized exactly
  int4 v = ((const int4*)nbr)[i];
  ((float4*)o)[i] = make_float4((float)v.x,(float)v.y,(float)v.z,(float)v.w);
}

// --------------------------------------------------------------------------
extern "C" void kernel_launch(void* const* d_in, const int* in_sizes, int n_in,
                              void* d_out, int out_size, void* d_ws, size_t ws_size,
                              hipStream_t stream) {
  const float* pts    = (const float*)d_in[0];
  const float* cov    = (const float*)d_in[1];
  const int*   nbr    = (const int*)  d_in[2];
  const float* pre_w  = (const float*)d_in[3];
  const float* pre_b  = (const float*)d_in[4];
  const float* pre_g  = (const float*)d_in[5];
  const float* pre_bb = (const float*)d_in[6];
  const float* kp     = (const float*)d_in[7];
  const float* kpw    = (const float*)d_in[8];
  const float* pos_w1 = (const float*)d_in[9];
  const float* pos_b1 = (const float*)d_in[10];
  const float* pos_g1 = (const float*)d_in[11];
  const float* pos_bb1= (const float*)d_in[12];
  const float* pos_w2 = (const float*)d_in[13];
  const float* pos_b2 = (const float*)d_in[14];
  const float* pos_g2 = (const float*)d_in[15];
  const float* pos_bb2= (const float*)d_in[16];
  const float* agg_w1 = (const float*)d_in[17];
  const float* agg_b1 = (const float*)d_in[18];
  const float* agg_g1 = (const float*)d_in[19];
  const float* agg_bb1= (const float*)d_in[20];
  const float* agg_w2 = (const float*)d_in[21];
  const float* agg_b2 = (const float*)d_in[22];
  const float* agg_g2 = (const float*)d_in[23];
  const float* agg_bb2= (const float*)d_in[24];
  const float* keep_w1= (const float*)d_in[25];
  const float* keep_b1= (const float*)d_in[26];
  const float* keep_g = (const float*)d_in[27];
  const float* keep_bb= (const float*)d_in[28];
  const float* keep_w2= (const float*)d_in[29];
  const float* keep_b2= (const float*)d_in[30];
  const float* uniq_w1= (const float*)d_in[31];
  const float* uniq_b1= (const float*)d_in[32];
  const float* uniq_g = (const float*)d_in[33];
  const float* uniq_bb= (const float*)d_in[34];
  const float* uniq_w2= (const float*)d_in[35];
  const float* uniq_b2= (const float*)d_in[36];

  float* out = (float*)d_out;     // f32 [match(N) | unique(N) | idx(N*K)]

  // ---- ws layout ----
  char* wsb = (char*)d_ws;
  size_t off = 0;
  float* stats = (float*)(wsb + off); off += 4096*4;   // stats[0..2303]; gcount at [2304]
  int*   gcount = (int*)(stats + 2304);
  unsigned short* wT = (unsigned short*)(wsb + off); off += (size_t)442368*2;
  unsigned short* kpwT   = wT;
  unsigned short* posw2T = wT + 245760;
  unsigned short* aggw1T = wT + 262144;
  unsigned short* aggw2T = wT + 294912;
  unsigned short* keepw1T= wT + 360448;
  unsigned short* uniqw1T= wT + 376832;
  float* fsum  = (float*)(wsb + off); off += (size_t)NPTS*4;
  float* invn  = (float*)(wsb + off); off += (size_t)NPTS*4;
  int*   list  = (int*)  (wsb + off); off += (size_t)NPTS*4;
  unsigned short* kpf  = (unsigned short*)(wsb + off); off += (size_t)NPTS*128*2;
  unsigned short* feat = (unsigned short*)(wsb + off); off += (size_t)NPTS*128*2;
  unsigned short* p2   = (unsigned short*)(wsb + off); off += (size_t)NPTS*256*2;
  unsigned short* a2   = (unsigned short*)(wsb + off); off += (size_t)NPTS*256*2;
  unsigned short* a1   = (unsigned short*)(wsb + off); off += (size_t)NPTS*256*2;
  unsigned short* preact = p2;            // dead before p2 written
  unsigned short* p1 = feat;              // feat dead after k_conv_act
  unsigned short* k1 = a1;                // a1 dead after agg2
  unsigned short* u1 = a1 + (size_t)NPTS*64;

  const double kpe = 1.0 / (cbrt(15.0) - 1.0) * 1.5;   // KP_EXTENT
  const float inv_ext = (float)(1.0 / kpe);
  const float ext2 = (float)(kpe * kpe);

  // zero stats + gcount
  hipMemsetAsync(stats, 0, 2308*sizeof(float), stream);

  k_wprep_all<<<1728, 256, 0, stream>>>(kpw, pos_w2, agg_w1, agg_w2,
                                        keep_w1, uniq_w1, wT);

  // pre layer
  k_pre<<<1250, 256, 0, stream>>>(cov, pre_w, pre_b, preact, stats + 0);
  k_prenorm<<<10000, 256, 0, stream>>>(preact, stats + 0, pre_g, pre_bb, feat, fsum);

  // sparse KPConv: scan + active-row conv
  k_scan<<<5000, 256, 0, stream>>>(pts, nbr, kp, fsum, kpf, invn,
                                   list, gcount, ext2);
  k_conv_act<<<1024, 256, 0, stream>>>(pts, nbr, kp, feat, kpwT, invn,
                                       list, gcount, kpf, ext2, inv_ext);

  // pos branch (p1 aliases feat)
  k_pos1<<<1250, 256, 0, stream>>>(pts, pos_w1, pos_b1, p1, stats + 256);
  k_gemm<<<dim3(625, 4), 256, 0, stream>>>(
      p1, stats + 256, pos_g1, pos_bb1, 64, 1,
      nullptr, nullptr, nullptr, nullptr, 0,
      posw2T, pos_b2, 256, p2, stats + 384);

  // agg branch
  k_gemm<<<dim3(625, 4), 256, 0, stream>>>(
      kpf, nullptr, nullptr, nullptr, 128, 0,
      nullptr, nullptr, nullptr, nullptr, 0,
      aggw1T, agg_b1, 256, a1, stats + 896);
  k_gemm<<<dim3(625, 4), 256, 0, stream>>>(
      a1, stats + 896, agg_g1, agg_bb1, 256, 1,
      nullptr, nullptr, nullptr, nullptr, 0,
      aggw2T, agg_b2, 256, a2, stats + 1408);

  // keep head
  k_gemm<<<dim3(625, 1), 256, 0, stream>>>(
      a2, stats + 1408, agg_g2, agg_bb2, 256, 1,
      nullptr, nullptr, nullptr, nullptr, 0,
      keepw1T, keep_b1, 64, k1, stats + 1920);
  k_head<<<10000, 256, 0, stream>>>(k1, stats + 1920, keep_g, keep_bb,
                                    keep_w2, keep_b2, out, 64);

  // uniq head
  k_gemm<<<dim3(625, 2), 256, 0, stream>>>(
      p2, stats + 384, pos_g2, pos_bb2, 256, 1,
      a2, stats + 1408, agg_g2, agg_bb2, 256,
      uniqw1T, uniq_b1, 128, u1, stats + 2048);
  k_head<<<10000, 256, 0, stream>>>(u1, stats + 2048, uniq_g, uniq_bb,
                                    uniq_w2, uniq_b2, out + NPTS, 128);

  // neighbors_index passthrough
  k_idx<<<1250, 256, 0, stream>>>(nbr, out + 2*NPTS);
}

// Round 8
// 314.704 us; speedup vs baseline: 2.6857x; 1.3037x over previous
//
#include <hip/hip_runtime.h>
#include <math.h>

// ---------------------------------------------------------------------------
// BimodalCompressor: KPConv point network (round 8)
// Sparse KPConv (row compaction) + SPARSE agg branch: only ~A (≈850) rows of
// kpf are nonzero; inactive rows of a1/a2/k1 are closed-form constant vectors.
// Dense a2/k1 = broadcast const + scatter of per-active-row GEMMs; BN stats =
// active sums + (N-A)*const fixups (exact). Wide-tile MFMA GEMMs for pos2/uniq.
// ---------------------------------------------------------------------------

#define NPTS 40000
#define KNB  32
#define PKP  15
#define SLOPE 0.01f
#define BNEPS 1e-5f
#define INV_N (1.0f/40000.0f)

typedef __attribute__((ext_vector_type(8))) short bf16x8;
typedef __attribute__((ext_vector_type(4))) float f32x4;

__device__ __forceinline__ float lrelu(float x){ return x >= 0.0f ? x : SLOPE*x; }
__device__ __forceinline__ unsigned short f2bf(float f){
  unsigned int b = __float_as_uint(f);
  b += 0x7fffu + ((b>>16)&1u);            // round-to-nearest-even
  return (unsigned short)(b>>16);
}
__device__ __forceinline__ float bf2f(unsigned short u){
  return __uint_as_float(((unsigned int)u)<<16);
}

// --------------------------------------------------------------------------
// K0: all weight transposes in one launch.
// --------------------------------------------------------------------------
__global__ __launch_bounds__(256) void k_wprep_all(
    const float* __restrict__ kpw,  const float* __restrict__ pw2,
    const float* __restrict__ aw1,  const float* __restrict__ aw2,
    const float* __restrict__ kw1,  const float* __restrict__ uw1,
    unsigned short* __restrict__ wT){
  int i = blockIdx.x*256 + threadIdx.x;   // grid exact: 442368
  const float* src; int K, N, off, li;
  if      (i < 245760){ src=kpw; K=1920; N=128; off=0;      li=i; }
  else if (i < 262144){ src=pw2; K=64;   N=256; off=245760; li=i-245760; }
  else if (i < 294912){ src=aw1; K=128;  N=256; off=262144; li=i-262144; }
  else if (i < 360448){ src=aw2; K=256;  N=256; off=294912; li=i-294912; }
  else if (i < 376832){ src=kw1; K=256;  N=64;  off=360448; li=i-360448; }
  else                { src=uw1; K=512;  N=128; off=376832; li=i-376832; }
  int k = li / N, n = li - k*N;
  wT[(size_t)off + (size_t)n*K + k] = f2bf(src[li]);
}

// --------------------------------------------------------------------------
// K1: preact(bf16) = cov[N,9] @ pre_w[9,128] + pre_b ; stats
// --------------------------------------------------------------------------
__global__ __launch_bounds__(256) void k_pre(
    const float* __restrict__ cov, const float* __restrict__ w,
    const float* __restrict__ b, unsigned short* __restrict__ preact,
    float* __restrict__ stats){
  __shared__ float sW[9*128];
  __shared__ float sX[32*9];
  __shared__ float sSum[2][128], sSq[2][128];
  int tid = threadIdx.x;
  int row0 = blockIdx.x*32;
  for (int i = tid; i < 9*128; i += 256) sW[i] = w[i];
  for (int i = tid; i < 32*9;  i += 256) sX[i] = cov[row0*9 + i];
  __syncthreads();
  int c = tid & 127, h = tid >> 7;
  float bias = b[c];
  float ls = 0.0f, lq = 0.0f;
  for (int r = h*16; r < h*16+16; ++r){
    float acc = bias;
    #pragma unroll
    for (int i = 0; i < 9; ++i) acc += sX[r*9+i]*sW[i*128+c];
    preact[(size_t)(row0+r)*128 + c] = f2bf(acc);
    ls += acc; lq += acc*acc;
  }
  sSum[h][c] = ls; sSq[h][c] = lq;
  __syncthreads();
  if (h == 0){
    atomicAdd(&stats[c],     sSum[0][c]+sSum[1][c]);
    atomicAdd(&stats[128+c], sSq[0][c]+sSq[1][c]);
  }
}

// --------------------------------------------------------------------------
// K2: feat(bf16) = lrelu(bn(preact)) ; fsum[n]
// --------------------------------------------------------------------------
__global__ __launch_bounds__(256) void k_prenorm(
    const unsigned short* __restrict__ preact, const float* __restrict__ stats,
    const float* __restrict__ g, const float* __restrict__ b,
    unsigned short* __restrict__ feat, float* __restrict__ fsum){
  int wid  = (int)((blockIdx.x*256 + threadIdx.x) >> 6);
  int lane = threadIdx.x & 63;
  if (wid >= NPTS) return;
  float su = stats[lane], sq = stats[128+lane];
  float mean = su*INV_N, var = sq*INV_N - mean*mean;
  float s0 = g[lane]*rsqrtf(var+BNEPS), h0 = b[lane]-mean*s0;
  su = stats[64+lane]; sq = stats[192+lane];
  mean = su*INV_N; var = sq*INV_N - mean*mean;
  float s1 = g[64+lane]*rsqrtf(var+BNEPS), h1 = b[64+lane]-mean*s1;
  size_t off = (size_t)wid*128;
  float f0 = lrelu(bf2f(preact[off+lane])*s0+h0);
  float f1 = lrelu(bf2f(preact[off+64+lane])*s1+h1);
  feat[off+lane]    = f2bf(f0);
  feat[off+64+lane] = f2bf(f1);
  float t = f0 + f1;
  #pragma unroll
  for (int o = 32; o; o >>= 1) t += __shfl_down(t, o, 64);
  if (lane == 0) fsum[wid] = t;
}

// --------------------------------------------------------------------------
// K3a scan: half-wave per row; invn[n]; active rows appended to list.
// --------------------------------------------------------------------------
__global__ __launch_bounds__(256) void k_scan(
    const float* __restrict__ pts, const int* __restrict__ nbr,
    const float* __restrict__ kp, const float* __restrict__ fsum,
    float* __restrict__ invn, int* __restrict__ list,
    int* __restrict__ gcount, float ext2){
  __shared__ float sKP[45];
  if (threadIdx.x < 45) sKP[threadIdx.x] = kp[threadIdx.x];
  __syncthreads();
  int wv   = (blockIdx.x*256 + threadIdx.x) >> 6;
  int lane = threadIdx.x & 63;
  int half = lane >> 5;
  int kk   = lane & 31;
  int n    = wv*2 + half;
  float px = pts[n*3+0], py = pts[n*3+1], pz = pts[n*3+2];
  int j = nbr[(size_t)n*KNB + kk];
  float nx = pts[j*3+0] - px;
  float ny = pts[j*3+1] - py;
  float nz = pts[j*3+2] - pz;
  float fs = fsum[j];
  bool anyp = false;
  #pragma unroll
  for (int p = 0; p < PKP; ++p){
    float dx = nx - sKP[p*3+0], dy = ny - sKP[p*3+1], dz = nz - sKP[p*3+2];
    anyp |= (dx*dx + dy*dy + dz*dz < ext2);
  }
  unsigned long long act  = __ballot(anyp);
  unsigned long long good = __ballot(fs > 0.0f);
  unsigned int actH  = half ? (unsigned int)(act  >> 32) : (unsigned int)act;
  unsigned int goodH = half ? (unsigned int)(good >> 32) : (unsigned int)good;
  if (kk == 0){
    int cnt = __popc(goodH);
    invn[n] = 1.0f / (float)(cnt < 1 ? 1 : cnt);
    if (actH){
      int pos = atomicAdd(gcount, 1);
      list[pos] = n;
    }
  }
}

// --------------------------------------------------------------------------
// K3b: conv for active rows -> COMPACT kpfc[it][128].
// --------------------------------------------------------------------------
__global__ __launch_bounds__(256) void k_conv_act(
    const float* __restrict__ pts, const int* __restrict__ nbr,
    const float* __restrict__ kp, const unsigned short* __restrict__ feat,
    const unsigned short* __restrict__ kpwT, const float* __restrict__ invn,
    const int* __restrict__ list, const int* __restrict__ gcount,
    unsigned short* __restrict__ kpfc, float ext2, float inv_ext){
  __shared__ float sW[PKP*128];
  __shared__ float sInfl[KNB*16];
  __shared__ unsigned int sPairP[KNB];
  __shared__ float sKP[45];
  __shared__ float sOut[128];
  __shared__ unsigned int sPmask, sPact;
  int tid = threadIdx.x;
  if (tid < 45) sKP[tid] = kp[tid];
  int cnt = *gcount;
  for (int it = blockIdx.x; it < cnt; it += gridDim.x){
    int n = list[it];
    if (tid == 0){ sPmask = 0u; sPact = 0u; }
    for (int i = tid; i < PKP*128; i += 256) sW[i] = 0.0f;
    __syncthreads();
    if (tid < KNB){
      int j = nbr[(size_t)n*KNB + tid];
      float nx = pts[j*3+0] - pts[n*3+0];
      float ny = pts[j*3+1] - pts[n*3+1];
      float nz = pts[j*3+2] - pts[n*3+2];
      unsigned int pm = 0u;
      #pragma unroll
      for (int p = 0; p < PKP; ++p){
        float dx = nx - sKP[p*3+0], dy = ny - sKP[p*3+1], dz = nz - sKP[p*3+2];
        float d2 = dx*dx + dy*dy + dz*dz;
        float infl = 0.0f;
        if (d2 < ext2){ infl = 1.0f - sqrtf(d2)*inv_ext; pm |= (1u << p); }
        sInfl[tid*16 + p] = infl;
      }
      sPairP[tid] = pm;
      if (pm){
        atomicOr(&sPact, 1u << tid);
        atomicOr(&sPmask, pm);
      }
    }
    __syncthreads();
    if (tid < 128){
      int c = tid;
      unsigned int m = sPact;
      while (m){
        int k = __ffs(m) - 1; m &= m - 1;
        int j = nbr[(size_t)n*KNB + k];
        float f = bf2f(feat[(size_t)j*128 + c]);
        unsigned int pp = sPairP[k];
        while (pp){
          int p = __ffs(pp) - 1; pp &= pp - 1;
          sW[p*128 + c] += sInfl[k*16 + p] * f;
        }
      }
    }
    __syncthreads();
    int d = tid & 127, h = tid >> 7;
    float acc = 0.0f;
    unsigned int pm = sPmask;
    while (pm){
      int p = __ffs(pm) - 1; pm &= pm - 1;
      const unsigned short* wp = kpwT + (size_t)d*1920 + p*128 + h*64;
      const float* wsrc = &sW[p*128 + h*64];
      #pragma unroll
      for (int c8 = 0; c8 < 8; ++c8){
        uint4 v = *(const uint4*)(wp + c8*8);
        unsigned int e[4] = {v.x, v.y, v.z, v.w};
        #pragma unroll
        for (int q = 0; q < 4; ++q){
          acc += wsrc[c8*8 + 2*q]     * bf2f((unsigned short)(e[q] & 0xffff));
          acc += wsrc[c8*8 + 2*q + 1] * bf2f((unsigned short)(e[q] >> 16));
        }
      }
    }
    if (h == 0) sOut[d] = acc;
    __syncthreads();
    if (h == 1) kpfc[(size_t)it*128 + d] = f2bf((sOut[d] + acc) * invn[n]);
    __syncthreads();
  }
}

// --------------------------------------------------------------------------
// K4: per-active-row GEMM. Y[yi] = lrelu?(bn?(X[xi])) @ Wt + bias.
// xi = xCompact? it : list[it]; same for yi. Active-row stats accumulated.
// One block processes rows it = blockIdx.x + s*gridDim.x. 256 thr; col=tid.
// --------------------------------------------------------------------------
__global__ __launch_bounds__(256) void k_rowgemm(
    const unsigned short* __restrict__ X, int xCompact,
    const float* __restrict__ st, const float* __restrict__ g,
    const float* __restrict__ bb, int K, int norm,
    const unsigned short* __restrict__ Wt, const float* __restrict__ bias,
    int NOUT, unsigned short* __restrict__ Y, int yCompact,
    float* __restrict__ statsOut,
    const int* __restrict__ list, const int* __restrict__ gcount){
  __shared__ float xs[256];
  __shared__ float sSc[256], sSh[256];
  int tid = threadIdx.x;
  if (norm && tid < K){
    float s = st[tid], q = st[K+tid];
    float mean = s*INV_N, var = q*INV_N - mean*mean;
    float sc = g[tid]*rsqrtf(var+BNEPS);
    sSc[tid] = sc; sSh[tid] = bb[tid] - mean*sc;
  }
  __syncthreads();
  int cnt = *gcount;
  float rs = 0.0f, rq = 0.0f;
  for (int it = blockIdx.x; it < cnt; it += gridDim.x){
    int n = list[it];
    int xi = xCompact ? it : n;
    if (tid < K){
      float xv = bf2f(X[(size_t)xi*K + tid]);
      if (norm) xv = lrelu(xv*sSc[tid] + sSh[tid]);
      xs[tid] = xv;
    }
    __syncthreads();
    if (tid < NOUT){
      float acc = bias[tid];
      const unsigned short* wp = Wt + (size_t)tid*K;
      for (int k8 = 0; k8 < K; k8 += 8){
        uint4 v = *(const uint4*)(wp + k8);
        unsigned int e[4] = {v.x, v.y, v.z, v.w};
        #pragma unroll
        for (int q = 0; q < 4; ++q){
          acc += xs[k8+2*q]   * bf2f((unsigned short)(e[q] & 0xffff));
          acc += xs[k8+2*q+1] * bf2f((unsigned short)(e[q] >> 16));
        }
      }
      int yi = yCompact ? it : n;
      Y[(size_t)yi*NOUT + tid] = f2bf(acc);
      rs += acc; rq += acc*acc;
    }
    __syncthreads();
  }
  if (tid < NOUT && rs != 0.0f){
    atomicAdd(&statsOut[tid],      rs);
    atomicAdd(&statsOut[NOUT+tid], rq);
  }
}

// --------------------------------------------------------------------------
// K5 const: single block. stats fixup (+= (N-A)*{vin,vin^2}); optionally
// xconst = lrelu(bn(vin)), vout = xconst @ Wt + bias (f32 + packed bf16).
// --------------------------------------------------------------------------
__global__ __launch_bounds__(256) void k_const(
    const float* __restrict__ vin, float* __restrict__ statsX, int K,
    const float* __restrict__ g, const float* __restrict__ bb,
    const unsigned short* __restrict__ Wt, const float* __restrict__ bias,
    int NOUT, float* __restrict__ vout, unsigned int* __restrict__ voutU,
    const int* __restrict__ gcount){
  __shared__ float sX[256];
  __shared__ float sV[256];
  int tid = threadIdx.x;
  float fN = (float)(NPTS - *gcount);
  if (tid < K){
    float s = vin[tid];
    statsX[tid]   += fN*s;
    statsX[K+tid] += fN*s*s;
  }
  __syncthreads();
  if (NOUT > 0){
    if (tid < K){
      float s = statsX[tid], q = statsX[K+tid];
      float mean = s*INV_N, var = q*INV_N - mean*mean;
      float sc = g[tid]*rsqrtf(var+BNEPS);
      sX[tid] = lrelu(vin[tid]*sc + bb[tid] - mean*sc);
    }
    __syncthreads();
    if (tid < NOUT){
      float acc = bias[tid];
      const unsigned short* wp = Wt + (size_t)tid*K;
      for (int k8 = 0; k8 < K; k8 += 8){
        uint4 v = *(const uint4*)(wp + k8);
        unsigned int e[4] = {v.x, v.y, v.z, v.w};
        #pragma unroll
        for (int q = 0; q < 4; ++q){
          acc += sX[k8+2*q]   * bf2f((unsigned short)(e[q] & 0xffff));
          acc += sX[k8+2*q+1] * bf2f((unsigned short)(e[q] >> 16));
        }
      }
      vout[tid] = acc; sV[tid] = acc;
    }
    __syncthreads();
    if (tid < NOUT/2)
      voutU[tid] = (unsigned int)f2bf(sV[2*tid]) |
                   ((unsigned int)f2bf(sV[2*tid+1]) << 16);
  }
}

// --------------------------------------------------------------------------
// K6 fill: dense broadcast of packed-bf16 const row. rowUints = 1<<shift.
// --------------------------------------------------------------------------
__global__ __launch_bounds__(256) void k_fill(
    unsigned int* __restrict__ Y, const unsigned int* __restrict__ vU,
    int shift, int total){
  int i = blockIdx.x*256 + threadIdx.x;
  int stride = gridDim.x*256;
  unsigned int msk = (1u << shift) - 1u;
  for (; i < total; i += stride) Y[i] = vU[i & msk];
}

// --------------------------------------------------------------------------
// K7 wide MFMA GEMM (NOUT = NCF*16 handled by one block; X loaded once).
// --------------------------------------------------------------------------
template<int NCF>
__global__ __launch_bounds__(256) void k_gemmw(
    const unsigned short* __restrict__ X0, const float* __restrict__ st0,
    const float* __restrict__ g0, const float* __restrict__ b0,
    int K0, int norm0,
    const unsigned short* __restrict__ X1, const float* __restrict__ st1,
    const float* __restrict__ g1, const float* __restrict__ b1, int K1,
    const unsigned short* __restrict__ Wt, const float* __restrict__ bias,
    unsigned short* __restrict__ Y, float* __restrict__ statsOut){
  const int NOUT = NCF*16;
  __shared__ unsigned short sA[64*64];
  __shared__ unsigned short sB[NOUT*64];
  __shared__ float sSc[64], sSh[64];
  __shared__ float sSum[NOUT], sSq[NOUT];
  int tid = threadIdx.x;
  int row0 = blockIdx.x*64;
  int w = tid >> 6, l = tid & 63;
  int KT = K0 + K1;
  if (tid < NOUT){ sSum[tid] = 0.0f; sSq[tid] = 0.0f; }
  f32x4 acc[NCF] = {};
  for (int kc = 0; kc < KT; kc += 64){
    bool sel1 = (kc >= K0);
    const unsigned short* Xp = sel1 ? X1 : X0;
    int Ks = sel1 ? K1 : K0;
    int cb = sel1 ? kc - K0 : kc;
    int nf = sel1 ? 1 : norm0;
    if (tid < 64 && nf){
      const float* st = sel1 ? st1 : st0;
      const float* gg = sel1 ? g1 : g0;
      const float* bb = sel1 ? b1 : b0;
      int ch = cb + tid;
      float s = st[ch], q = st[Ks+ch];
      float mean = s*INV_N, var = q*INV_N - mean*mean;
      float sc = gg[ch]*rsqrtf(var+BNEPS);
      sSc[tid] = sc; sSh[tid] = bb[ch] - mean*sc;
    }
    __syncthreads();
    #pragma unroll
    for (int p = 0; p < 2; ++p){
      int r = (tid >> 3) + p*32;
      int k0 = (tid & 7)*8;
      uint4 v = *(const uint4*)(Xp + (size_t)(row0+r)*Ks + cb + k0);
      if (nf){
        unsigned short e[8] = {(unsigned short)(v.x&0xffff),(unsigned short)(v.x>>16),
                               (unsigned short)(v.y&0xffff),(unsigned short)(v.y>>16),
                               (unsigned short)(v.z&0xffff),(unsigned short)(v.z>>16),
                               (unsigned short)(v.w&0xffff),(unsigned short)(v.w>>16)};
        unsigned short o[8];
        #pragma unroll
        for (int j = 0; j < 8; ++j)
          o[j] = f2bf(lrelu(bf2f(e[j])*sSc[k0+j] + sSh[k0+j]));
        v.x = (uint)o[0] | ((uint)o[1]<<16);
        v.y = (uint)o[2] | ((uint)o[3]<<16);
        v.z = (uint)o[4] | ((uint)o[5]<<16);
        v.w = (uint)o[6] | ((uint)o[7]<<16);
      }
      int byteA = (r*128 + k0*2) ^ ((r&7)<<4);
      *(uint4*)((char*)sA + byteA) = v;
    }
    #pragma unroll
    for (int ps = 0; ps < NCF/2; ++ps){
      int idx = ps*256 + tid;
      int r = idx >> 3, s = idx & 7;
      uint4 vb = *(const uint4*)(Wt + (size_t)r*KT + kc + s*8);
      int byteB = (r*128 + s*16) ^ ((r&7)<<4);
      *(uint4*)((char*)sB + byteB) = vb;
    }
    __syncthreads();
    int rowA = w*16 + (l & 15);
    #pragma unroll
    for (int m = 0; m < 2; ++m){
      int ka = m*32 + (l >> 4)*8;
      int byteA = (rowA*128 + ka*2) ^ ((rowA&7)<<4);
      bf16x8 af = *(const bf16x8*)((const char*)sA + byteA);
      #pragma unroll
      for (int cf = 0; cf < NCF; ++cf){
        int colB = cf*16 + (l & 15);
        int byteB = (colB*128 + ka*2) ^ ((colB&7)<<4);
        bf16x8 bfr = *(const bf16x8*)((const char*)sB + byteB);
        acc[cf] = __builtin_amdgcn_mfma_f32_16x16x32_bf16(af, bfr, acc[cf], 0, 0, 0);
      }
    }
    __syncthreads();
  }
  float cs[NCF], cq[NCF];
  #pragma unroll
  for (int cf = 0; cf < NCF; ++cf){
    int col = cf*16 + (l & 15);
    float bj = bias[col];
    cs[cf] = 0.0f; cq[cf] = 0.0f;
    #pragma unroll
    for (int r = 0; r < 4; ++r){
      int grow = row0 + w*16 + (l >> 4)*4 + r;
      float v = acc[cf][r] + bj;
      Y[(size_t)grow*NOUT + col] = f2bf(v);
      cs[cf] += v; cq[cf] += v*v;
    }
  }
  #pragma unroll
  for (int cf = 0; cf < NCF; ++cf){
    atomicAdd(&sSum[cf*16 + (l&15)], cs[cf]);
    atomicAdd(&sSq[cf*16 + (l&15)],  cq[cf]);
  }
  __syncthreads();
  if (tid < NOUT){
    atomicAdd(&statsOut[tid],      sSum[tid]);
    atomicAdd(&statsOut[NOUT+tid], sSq[tid]);
  }
}

// --------------------------------------------------------------------------
// K8: p1(bf16) = points @ pos_w1 + b ; stats
// --------------------------------------------------------------------------
__global__ __launch_bounds__(256) void k_pos1(
    const float* __restrict__ pts, const float* __restrict__ w,
    const float* __restrict__ b, unsigned short* __restrict__ p1,
    float* __restrict__ stats){
  __shared__ float sSum[4][64], sSq[4][64];
  int tid = threadIdx.x;
  int c = tid & 63, grp = tid >> 6;
  int row0 = blockIdx.x*32;
  float w0 = w[c], w1 = w[64+c], w2 = w[128+c], bb = b[c];
  float ls = 0.0f, lq = 0.0f;
  for (int r = row0 + grp*8; r < row0 + grp*8 + 8; ++r){
    float x0 = pts[r*3+0], x1 = pts[r*3+1], x2 = pts[r*3+2];
    float y = bb + x0*w0 + x1*w1 + x2*w2;
    p1[(size_t)r*64 + c] = f2bf(y);
    ls += y; lq += y*y;
  }
  sSum[grp][c] = ls; sSq[grp][c] = lq;
  __syncthreads();
  if (grp == 0){
    atomicAdd(&stats[c],    sSum[0][c]+sSum[1][c]+sSum[2][c]+sSum[3][c]);
    atomicAdd(&stats[64+c], sSq[0][c]+sSq[1][c]+sSq[2][c]+sSq[3][c]);
  }
}

// --------------------------------------------------------------------------
// K9 head: out[n] = sigmoid( sum_c lrelu(bn(H[n,c]))*w2[c] + b2 )
// --------------------------------------------------------------------------
__global__ __launch_bounds__(256) void k_head(
    const unsigned short* __restrict__ H, const float* __restrict__ stats,
    const float* __restrict__ g, const float* __restrict__ b,
    const float* __restrict__ w2, const float* __restrict__ b2,
    float* __restrict__ out, int Cdim){
  int wid  = (int)((blockIdx.x*256 + threadIdx.x) >> 6);
  int lane = threadIdx.x & 63;
  if (wid >= NPTS) return;
  float acc = 0.0f;
  for (int c = lane; c < Cdim; c += 64){
    float su = stats[c], sq = stats[Cdim+c];
    float mean = su*INV_N, var = sq*INV_N - mean*mean;
    float sc = g[c]*rsqrtf(var+BNEPS), sh = b[c]-mean*sc;
    float h = lrelu(bf2f(H[(size_t)wid*Cdim + c])*sc + sh);
    acc += h * w2[c];
  }
  #pragma unroll
  for (int o = 32; o; o >>= 1) acc += __shfl_down(acc, o, 64);
  if (lane == 0){
    float x = acc + b2[0];
    out[wid] = 1.0f/(1.0f + expf(-x));
  }
}

// --------------------------------------------------------------------------
// K10: neighbors_index passthrough as float32
// --------------------------------------------------------------------------
__global__ __launch_bounds__(256) void k_idx(
    const int* __restrict__ nbr, float* __restrict__ o){
  int i = blockIdx.x*256 + threadIdx.x;
  int4 v = ((const int4*)nbr)[i];
  ((float4*)o)[i] = make_float4((float)v.x,(float)v.y,(float)v.z,(float)v.w);
}

// --------------------------------------------------------------------------
extern "C" void kernel_launch(void* const* d_in, const int* in_sizes, int n_in,
                              void* d_out, int out_size, void* d_ws, size_t ws_size,
                              hipStream_t stream) {
  const float* pts    = (const float*)d_in[0];
  const float* cov    = (const float*)d_in[1];
  const int*   nbr    = (const int*)  d_in[2];
  const float* pre_w  = (const float*)d_in[3];
  const float* pre_b  = (const float*)d_in[4];
  const float* pre_g  = (const float*)d_in[5];
  const float* pre_bb = (const float*)d_in[6];
  const float* kp     = (const float*)d_in[7];
  const float* kpw    = (const float*)d_in[8];
  const float* pos_w1 = (const float*)d_in[9];
  const float* pos_b1 = (const float*)d_in[10];
  const float* pos_g1 = (const float*)d_in[11];
  const float* pos_bb1= (const float*)d_in[12];
  const float* pos_w2 = (const float*)d_in[13];
  const float* pos_b2 = (const float*)d_in[14];
  const float* pos_g2 = (const float*)d_in[15];
  const float* pos_bb2= (const float*)d_in[16];
  const float* agg_w1 = (const float*)d_in[17];
  const float* agg_b1 = (const float*)d_in[18];
  const float* agg_g1 = (const float*)d_in[19];
  const float* agg_bb1= (const float*)d_in[20];
  const float* agg_w2 = (const float*)d_in[21];
  const float* agg_b2 = (const float*)d_in[22];
  const float* agg_g2 = (const float*)d_in[23];
  const float* agg_bb2= (const float*)d_in[24];
  const float* keep_w1= (const float*)d_in[25];
  const float* keep_b1= (const float*)d_in[26];
  const float* keep_g = (const float*)d_in[27];
  const float* keep_bb= (const float*)d_in[28];
  const float* keep_w2= (const float*)d_in[29];
  const float* keep_b2= (const float*)d_in[30];
  const float* uniq_w1= (const float*)d_in[31];
  const float* uniq_b1= (const float*)d_in[32];
  const float* uniq_g = (const float*)d_in[33];
  const float* uniq_bb= (const float*)d_in[34];
  const float* uniq_w2= (const float*)d_in[35];
  const float* uniq_b2= (const float*)d_in[36];

  float* out = (float*)d_out;     // f32 [match(N) | unique(N) | idx(N*K)]

  // ---- ws layout ----
  char* wsb = (char*)d_ws;
  size_t off = 0;
  float* stats = (float*)(wsb + off); off += 4096*4;
  int*   gcount = (int*)(stats + 2304);
  float* v2  = stats + 2560;                       // [256]
  unsigned int* v2u = (unsigned int*)(stats + 2816);  // [128]
  float* v3  = stats + 2944;                       // [64]
  unsigned int* v3u = (unsigned int*)(stats + 3008);  // [32]
  unsigned short* wT = (unsigned short*)(wsb + off); off += (size_t)442368*2;
  unsigned short* kpwT   = wT;
  unsigned short* posw2T = wT + 245760;
  unsigned short* aggw1T = wT + 262144;
  unsigned short* aggw2T = wT + 294912;
  unsigned short* keepw1T= wT + 360448;
  unsigned short* uniqw1T= wT + 376832;
  float* fsum  = (float*)(wsb + off); off += (size_t)NPTS*4;
  float* invn  = (float*)(wsb + off); off += (size_t)NPTS*4;
  int*   list  = (int*)  (wsb + off); off += (size_t)NPTS*4;
  unsigned short* feat = (unsigned short*)(wsb + off); off += (size_t)NPTS*128*2;
  unsigned short* kpfc = (unsigned short*)(wsb + off); off += (size_t)NPTS*128*2;
  unsigned short* a1c  = (unsigned short*)(wsb + off); off += (size_t)NPTS*256*2;
  unsigned short* a2   = (unsigned short*)(wsb + off); off += (size_t)NPTS*256*2;
  unsigned short* k1   = (unsigned short*)(wsb + off); off += (size_t)NPTS*64*2;
  // aliases (into dead regions):
  unsigned short* preact = a2;     // dead before a2 fill
  unsigned short* p1 = feat;       // feat dead after k_conv_act
  unsigned short* p2 = a1c;        // a1c dead after agg2 rowgemm
  unsigned short* u1 = kpfc;       // kpfc dead after agg1 rowgemm

  const double kpe = 1.0 / (cbrt(15.0) - 1.0) * 1.5;   // KP_EXTENT
  const float inv_ext = (float)(1.0 / kpe);
  const float ext2 = (float)(kpe * kpe);

  hipMemsetAsync(stats, 0, 2308*sizeof(float), stream);

  k_wprep_all<<<1728, 256, 0, stream>>>(kpw, pos_w2, agg_w1, agg_w2,
                                        keep_w1, uniq_w1, wT);

  // pre layer
  k_pre<<<1250, 256, 0, stream>>>(cov, pre_w, pre_b, preact, stats + 0);
  k_prenorm<<<10000, 256, 0, stream>>>(preact, stats + 0, pre_g, pre_bb, feat, fsum);

  // sparse KPConv
  k_scan<<<5000, 256, 0, stream>>>(pts, nbr, kp, fsum, invn, list, gcount, ext2);
  k_conv_act<<<1024, 256, 0, stream>>>(pts, nbr, kp, feat, kpwT, invn,
                                       list, gcount, kpfc, ext2, inv_ext);

  // pos1 (p1 aliases feat; feat dead after conv_act)
  k_pos1<<<1250, 256, 0, stream>>>(pts, pos_w1, pos_b1, p1, stats + 256);

  // ---- sparse agg branch ----
  // agg1: a1c[it] = kpfc[it] @ aggw1T + b1 ; active stats -> stats+896
  k_rowgemm<<<256, 256, 0, stream>>>(
      kpfc, 1, nullptr, nullptr, nullptr, 128, 0,
      aggw1T, agg_b1, 256, a1c, 1, stats + 896, list, gcount);
  // const1: fixup stats+896 with b1; x1c = lrelu(bn1(b1)); v2 = x1c@aggw2T+b2
  k_const<<<1, 256, 0, stream>>>(
      agg_b1, stats + 896, 256, agg_g1, agg_bb1,
      aggw2T, agg_b2, 256, v2, v2u, gcount);
  // fill dense a2 with v2
  k_fill<<<2048, 256, 0, stream>>>((unsigned int*)a2, v2u, 7, NPTS*128);
  // agg2: a2[list[it]] = lrelu(bn1(a1c[it]))@aggw2T + b2 ; stats+1408 active
  k_rowgemm<<<256, 256, 0, stream>>>(
      a1c, 1, stats + 896, agg_g1, agg_bb1, 256, 1,
      aggw2T, agg_b2, 256, a2, 0, stats + 1408, list, gcount);
  // const2: fixup stats+1408 with v2; x2c = lrelu(bn2(v2)); v3 = x2c@keepw1T+kb1
  k_const<<<1, 256, 0, stream>>>(
      v2, stats + 1408, 256, agg_g2, agg_bb2,
      keepw1T, keep_b1, 64, v3, v3u, gcount);
  // fill dense k1 with v3
  k_fill<<<2048, 256, 0, stream>>>((unsigned int*)k1, v3u, 5, NPTS*32);
  // keep: k1[list[it]] = lrelu(bn2(a2[list[it]]))@keepw1T + kb1 ; stats+1920
  k_rowgemm<<<256, 256, 0, stream>>>(
      a2, 0, stats + 1408, agg_g2, agg_bb2, 256, 1,
      keepw1T, keep_b1, 64, k1, 0, stats + 1920, list, gcount);
  // const3: fixup stats+1920 with v3 (no const output)
  k_const<<<1, 256, 0, stream>>>(
      v3, stats + 1920, 64, nullptr, nullptr,
      nullptr, nullptr, 0, nullptr, nullptr, gcount);

  // pos2 (wide tile; p2 aliases a1c - dead after agg2 rowgemm)
  k_gemmw<16><<<625, 256, 0, stream>>>(
      p1, stats + 256, pos_g1, pos_bb1, 64, 1,
      nullptr, nullptr, nullptr, nullptr, 0,
      posw2T, pos_b2, p2, stats + 384);

  // keep head (dense k1, stats final)
  k_head<<<10000, 256, 0, stream>>>(k1, stats + 1920, keep_g, keep_bb,
                                    keep_w2, keep_b2, out, 64);

  // uniq: u1 = [p2 norm | a2 norm] @ uniqw1T + ub1  (u1 aliases kpfc)
  k_gemmw<8><<<625, 256, 0, stream>>>(
      p2, stats + 384, pos_g2, pos_bb2, 256, 1,
      a2, stats + 1408, agg_g2, agg_bb2, 256,
      uniqw1T, uniq_b1, u1, stats + 2048);
  k_head<<<10000, 256, 0, stream>>>(u1, stats + 2048, uniq_g, uniq_bb,
                                    uniq_w2, uniq_b2, out + NPTS, 128);

  // neighbors_index passthrough
  k_idx<<<1250, 256, 0, stream>>>(nbr, out + 2*NPTS);
}